// Round 3
// 1612.816 us; speedup vs baseline: 1.0233x; 1.0233x over previous
//
#include <hip/hip_runtime.h>

// ---------------------------------------------------------------------------
// TransformerSeqLayer on MI355X.
// Banded (window 1024) rel-pos attention + LN + top-2 MoE + momentum + LN.
// Precision: gate-feeding path uses 2-way bf16-split MFMA (3 MFMAs); MoE
// experts single bf16. This round: LDS XOR-swizzle (kill 8-way bank conflict
// on ds_read_b128 fragment loads; swizzled global source + swizzled read,
// linear global_load_lds dest per rule-21) + Z-GEMM K-split 4 -> 2.
// (Resubmit x2: container acquisition failed twice; source diff audited —
// no OOB / no launch pathology; infra failure, not kernel.)
// ---------------------------------------------------------------------------

typedef short short8 __attribute__((ext_vector_type(8)));
typedef float f32x4 __attribute__((ext_vector_type(4)));

typedef const void __attribute__((address_space(1)))* gas1_t;
typedef void __attribute__((address_space(3)))* las3_t;
#define ASYNC16(G, L) __builtin_amdgcn_global_load_lds((gas1_t)(G), (las3_t)(L), 16, 0, 0)

#define DEV __device__ __forceinline__

DEV float bf2f(unsigned short u) {
  union { unsigned int u; float f; } x; x.u = ((unsigned int)u) << 16; return x.f;
}
DEV unsigned short f2bf(float f) {
  union { float f; unsigned int u; } x; x.f = f;
  unsigned int r = x.u + 0x7fffu + ((x.u >> 16) & 1u);
  return (unsigned short)(r >> 16);
}

// ---------------------------------------------------------------------------
// Generic 128x128 MFMA GEMM. C[m,n] = sum_k A[m,k]*BT[n,k].
// grid.x = nx * kchunks (bxn = bx%nx selects N-tile, kc = bx/nx selects K chunk
// of length Kc). tmap mode (MoE): by indexes a compact tile list (expert, slot
// base); idx!=null gathers A rows through bucket.
// Modes: 0 fp32+bias store, 1 split-bf16 store, 2 split-bf16 transposed store,
//        3 score epilogue (+Ppos skew lookup, mask, /32), 4 bias+relu+bf16,
//        5 atomicAdd fp32 (+bias only when kc==0).
// LDS tiles are [128][32] shorts with chunk-XOR swizzle: LDS[r][c8] holds
// global chunk c8 ^ ((r>>1)&3)  (chunks of 8 shorts = 16B). The staging
// source column is pre-swizzled so global_load_lds' linear dest lands data
// swizzled; fragment reads apply the same XOR -> conflict-free ds_read_b128.
// ---------------------------------------------------------------------------
struct GemmP {
  const unsigned short* Ah; const unsigned short* Al;
  const unsigned short* Bh; const unsigned short* Bl;
  void* C; void* C2;
  const float* bias;
  const float* xtra;
  const int* idx; const int2* tmap; const int* tn;
  long a_zo, a_zi;
  long b_zo, b_zi, b_y;
  long c_zo, c_zi, c_y, c_x;
  long x_zo, x_zi, x_y;
  long bias_z;
  int lda, ldb, ldc, xld;
  int K, Kc, nx, zdiv, mode, split;
};

__global__ __launch_bounds__(256) void kGemm(GemmP p) {
  const int t = threadIdx.x;
  const int bx = blockIdx.x, by = blockIdx.y, bz = blockIdx.z;
  const int zo = bz / p.zdiv, zi = bz % p.zdiv;
  const int bxn = bx % p.nx, kc = bx / p.nx;

  long aOff = 0, bOff, cOff;
  long ar0, ar1;
  int e = zi;
  if (p.tmap) {
    if (by >= *p.tn) return;
    int2 tm = p.tmap[by];
    e = tm.x;
    long base = tm.y;
    cOff = base * p.ldc + (long)bxn * p.c_x;
    bOff = (long)e * p.b_zi + (long)bxn * 128L * p.ldb;
    if (p.idx) { ar0 = p.idx[base + (t >> 2)]; ar1 = p.idx[base + 64 + (t >> 2)]; }
    else { ar0 = base + (t >> 2); ar1 = ar0 + 64; }
  } else {
    aOff = (long)zo * p.a_zo + (long)zi * p.a_zi;
    bOff = (long)zo * p.b_zo + (long)zi * p.b_zi + (long)by * p.b_y + (long)bxn * 128L * p.ldb;
    cOff = (long)zo * p.c_zo + (long)zi * p.c_zi + (long)by * p.c_y + (long)bxn * p.c_x;
    ar0 = by * 128 + (t >> 2); ar1 = ar0 + 64;
  }

  // staging col, XOR-swizzled: chunk (t&3) ^ ((row>>1)&3) with row = t>>2
  const int scol = (((t & 3) ^ ((t >> 3) & 3)) << 3);
  const unsigned short* A0h = p.Ah + aOff + ar0 * (long)p.lda + scol;
  const unsigned short* A1h = p.Ah + aOff + ar1 * (long)p.lda + scol;
  const unsigned short* B0h = p.Bh + bOff + (long)(t >> 2) * p.ldb + scol;
  const unsigned short* B1h = B0h + 64L * p.ldb;
  const unsigned short *A0l = nullptr, *A1l = nullptr, *B0l = nullptr, *B1l = nullptr;
  if (p.split) {
    A0l = p.Al + aOff + ar0 * (long)p.lda + scol;
    A1l = p.Al + aOff + ar1 * (long)p.lda + scol;
    B0l = p.Bl + bOff + (long)(t >> 2) * p.ldb + scol;
    B1l = B0l + 64L * p.ldb;
  }

  __shared__ short sAh[4096], sAl[4096], sBh[4096], sBl[4096];
  const int wave = t >> 6;
  const int lane = t & 63;
  const int quad = lane >> 4, l15 = lane & 15;
  const int wr = (wave >> 1) * 64, wc = (wave & 1) * 64;
  // fragment-read chunk, same XOR: quad ^ ((row>>1)&3), row = ...16*i + l15
  const int qs = ((quad ^ ((l15 >> 1) & 3)) << 3);

  f32x4 acc[4][4] = {};
  const int kt0 = (kc * p.Kc) >> 5;
  const int ktN = kt0 + (p.Kc >> 5);
  for (int kt = kt0; kt < ktN; ++kt) {
    const int k0 = kt << 5;
    ASYNC16(A0h + k0, &sAh[wave * 512]);
    ASYNC16(A1h + k0, &sAh[2048 + wave * 512]);
    ASYNC16(B0h + k0, &sBh[wave * 512]);
    ASYNC16(B1h + k0, &sBh[2048 + wave * 512]);
    if (p.split) {
      ASYNC16(A0l + k0, &sAl[wave * 512]);
      ASYNC16(A1l + k0, &sAl[2048 + wave * 512]);
      ASYNC16(B0l + k0, &sBl[wave * 512]);
      ASYNC16(B1l + k0, &sBl[2048 + wave * 512]);
    }
    __syncthreads();
    short8 fa[4], fb[4];
#pragma unroll
    for (int i = 0; i < 4; ++i) {
      fa[i] = *(const short8*)&sAh[(wr + i * 16 + l15) * 32 + qs];
      fb[i] = *(const short8*)&sBh[(wc + i * 16 + l15) * 32 + qs];
    }
#pragma unroll
    for (int bi = 0; bi < 4; ++bi)
#pragma unroll
      for (int bj = 0; bj < 4; ++bj)
        acc[bi][bj] = __builtin_amdgcn_mfma_f32_16x16x32_bf16(fa[bi], fb[bj], acc[bi][bj], 0, 0, 0);
    if (p.split) {
      short8 ga[4], gb[4];
#pragma unroll
      for (int i = 0; i < 4; ++i) {
        ga[i] = *(const short8*)&sAl[(wr + i * 16 + l15) * 32 + qs];
        gb[i] = *(const short8*)&sBl[(wc + i * 16 + l15) * 32 + qs];
      }
#pragma unroll
      for (int bi = 0; bi < 4; ++bi)
#pragma unroll
        for (int bj = 0; bj < 4; ++bj) {
          acc[bi][bj] = __builtin_amdgcn_mfma_f32_16x16x32_bf16(fa[bi], gb[bj], acc[bi][bj], 0, 0, 0);
          acc[bi][bj] = __builtin_amdgcn_mfma_f32_16x16x32_bf16(ga[bi], fb[bj], acc[bi][bj], 0, 0, 0);
        }
    }
    __syncthreads();
  }

  long xOff = 0;
  if (p.mode == 3) xOff = (long)zo * p.x_zo + (long)zi * p.x_zi + (long)by * p.x_y;
#pragma unroll
  for (int bj = 0; bj < 4; ++bj) {
    const int n_loc = wc + bj * 16 + l15;
    float bv = 0.0f;
    if (p.bias) bv = p.bias[(long)e * p.bias_z + (long)bxn * 128 + n_loc];
#pragma unroll
    for (int bi = 0; bi < 4; ++bi) {
#pragma unroll
      for (int r = 0; r < 4; ++r) {
        const int m_loc = wr + bi * 16 + quad * 4 + r;   // C/D: row=quad*4+reg, col=lane&15
        float v = acc[bi][bj][r];
        if (p.mode == 0) {
          ((float*)p.C)[cOff + (long)m_loc * p.ldc + n_loc] = v + bv;
        } else if (p.mode == 1) {
          long a = cOff + (long)m_loc * p.ldc + n_loc;
          unsigned short hv = f2bf(v);
          ((unsigned short*)p.C)[a] = hv;
          ((unsigned short*)p.C2)[a] = f2bf(v - bf2f(hv));
        } else if (p.mode == 2) {
          long a = cOff + (long)n_loc * p.ldc + m_loc;
          unsigned short hv = f2bf(v);
          ((unsigned short*)p.C)[a] = hv;
          ((unsigned short*)p.C2)[a] = f2bf(v - bf2f(hv));
        } else if (p.mode == 3) {
          int l = bxn * 128 + n_loc - m_loc;
          float outv;
          if ((unsigned)l < 1024u)
            outv = (v + p.xtra[xOff + (long)m_loc * p.xld + l]) * 0.03125f;
          else
            outv = -1e30f;
          ((float*)p.C)[cOff + (long)m_loc * p.ldc + n_loc] = outv;
        } else if (p.mode == 4) {
          float rv = v + bv;
          rv = rv > 0.0f ? rv : 0.0f;
          ((unsigned short*)p.C)[cOff + (long)m_loc * p.ldc + n_loc] = f2bf(rv);
        } else {  // mode 5: atomic fp32 accumulate, bias only in chunk 0
          float av = v + (kc == 0 ? bv : 0.0f);
          atomicAdd(&((float*)p.C)[cOff + (long)m_loc * p.ldc + n_loc], av);
        }
      }
    }
  }
}

// ---------------- prep kernels ----------------
__global__ __launch_bounds__(256) void kConcatSplit(const float* __restrict__ h,
                                                    const float* __restrict__ hc,
                                                    unsigned short* __restrict__ Xh,
                                                    unsigned short* __restrict__ Xl) {
  long i = (((long)blockIdx.x) * 256 + threadIdx.x) * 4;
  long b = i >> 21;
  long rem = i & 2097151;
  const float* s = (rem < 1048576) ? (hc + b * 1048576 + rem) : (h + b * 1048576 + (rem - 1048576));
  f32x4 v = *(const f32x4*)s;
#pragma unroll
  for (int j = 0; j < 4; ++j) {
    float x = v[j];
    unsigned short hi = f2bf(x);
    Xh[i + j] = hi;
    Xl[i + j] = f2bf(x - bf2f(hi));
  }
}

__global__ __launch_bounds__(256) void kTransposeSplit(const float* __restrict__ src, long src_z,
                                                       int R, int C,
                                                       unsigned short* __restrict__ dh,
                                                       unsigned short* __restrict__ dl, long dst_z) {
  __shared__ float tile[32][33];
  const int z = blockIdx.z;
  const float* s = src + (long)z * src_z;
  const int c0 = blockIdx.x * 32, r0 = blockIdx.y * 32;
  const int tx = threadIdx.x & 31, ty = threadIdx.x >> 5;
  for (int i = 0; i < 32; i += 8)
    tile[ty + i][tx] = s[(long)(r0 + ty + i) * C + c0 + tx];
  __syncthreads();
  unsigned short* ph = dh + (long)z * dst_z;
  for (int i = 0; i < 32; i += 8) {
    int c = c0 + ty + i;
    float v = tile[tx][ty + i];
    unsigned short hv = f2bf(v);
    ph[(long)c * R + r0 + tx] = hv;
    if (dl) dl[(long)z * dst_z + (long)c * R + r0 + tx] = f2bf(v - bf2f(hv));
  }
}

// fp32 -> hi/lo bf16 planes
__global__ __launch_bounds__(256) void kSplitF(const float* __restrict__ src,
                                               unsigned short* __restrict__ hi,
                                               unsigned short* __restrict__ lo, int n4) {
  int i = blockIdx.x * 256 + threadIdx.x;
  if (i >= n4) return;
  f32x4 v = ((const f32x4*)src)[i];
#pragma unroll
  for (int j = 0; j < 4; ++j) {
    float x = v[j];
    unsigned short h = f2bf(x);
    hi[i * 4 + j] = h;
    lo[i * 4 + j] = f2bf(x - bf2f(h));
  }
}

// ---------------- softmax over banded score rows (1152 slots) ----------------
__global__ __launch_bounds__(256) void kSoftmax(const float* __restrict__ S,
                                                unsigned short* __restrict__ Ph,
                                                unsigned short* __restrict__ Pl) {
  __shared__ float red[4];
  const long r = blockIdx.x;
  const float* s = S + r * 1152;
  const int t = threadIdx.x;
  float v[5];
  float mx = -3e38f;
#pragma unroll
  for (int i = 0; i < 5; ++i) {
    int c = t + i * 256;
    v[i] = (c < 1152) ? s[c] : -3e38f;
    mx = fmaxf(mx, v[i]);
  }
  for (int o = 32; o; o >>= 1) mx = fmaxf(mx, __shfl_xor(mx, o));
  if ((t & 63) == 0) red[t >> 6] = mx;
  __syncthreads();
  mx = fmaxf(fmaxf(red[0], red[1]), fmaxf(red[2], red[3]));
  __syncthreads();
  float e[5]; float sum = 0.f;
#pragma unroll
  for (int i = 0; i < 5; ++i) {
    int c = t + i * 256;
    e[i] = (c < 1152) ? expf(v[i] - mx) : 0.f;
    sum += e[i];
  }
  for (int o = 32; o; o >>= 1) sum += __shfl_xor(sum, o);
  if ((t & 63) == 0) red[t >> 6] = sum;
  __syncthreads();
  sum = red[0] + red[1] + red[2] + red[3];
  const float inv = 1.0f / sum;
#pragma unroll
  for (int i = 0; i < 5; ++i) {
    int c = t + i * 256;
    if (c < 1152) {
      float pv = e[i] * inv;
      unsigned short hv = f2bf(pv);
      Ph[r * 1152 + c] = hv;
      Pl[r * 1152 + c] = f2bf(pv - bf2f(hv));
    }
  }
}

// ---------------- layernorms ----------------
DEV float blockReduceSum(float v, float* red) {
  for (int o = 32; o; o >>= 1) v += __shfl_xor(v, o);
  if ((threadIdx.x & 63) == 0) red[threadIdx.x >> 6] = v;
  __syncthreads();
  v = red[0] + red[1] + red[2] + red[3];
  __syncthreads();
  return v;
}

__global__ __launch_bounds__(256) void kLN1(const float* __restrict__ h, const float* __restrict__ aw,
                                            const float* __restrict__ g, const float* __restrict__ b,
                                            float* __restrict__ h1f, unsigned short* __restrict__ h1h) {
  __shared__ float red[4];
  const long r = blockIdx.x;
  const int t = threadIdx.x;
  float x[4]; float s = 0.f;
#pragma unroll
  for (int i = 0; i < 4; ++i) { int c = t + i * 256; x[i] = h[r * 1024 + c] + aw[r * 1024 + c]; s += x[i]; }
  float mu = blockReduceSum(s, red) * (1.0f / 1024.0f);
  float q = 0.f;
#pragma unroll
  for (int i = 0; i < 4; ++i) { float d = x[i] - mu; q += d * d; }
  float var = blockReduceSum(q, red) * (1.0f / 1024.0f);
  float rstd = 1.0f / sqrtf(var + 1e-5f);
#pragma unroll
  for (int i = 0; i < 4; ++i) {
    int c = t + i * 256;
    float y = (x[i] - mu) * rstd * g[c] + b[c];
    h1f[r * 1024 + c] = y;
    h1h[r * 1024 + c] = f2bf(y);
  }
}

__global__ __launch_bounds__(256) void kLN2(const float* __restrict__ h1f, const float* __restrict__ mom,
                                            const float* __restrict__ g, const float* __restrict__ b,
                                            float* __restrict__ out) {
  __shared__ float red[4];
  const long r = blockIdx.x;
  const int t = threadIdx.x;
  float x[4]; float s = 0.f;
#pragma unroll
  for (int i = 0; i < 4; ++i) { int c = t + i * 256; x[i] = h1f[r * 1024 + c] - mom[r * 1024 + c]; s += x[i]; }
  float mu = blockReduceSum(s, red) * (1.0f / 1024.0f);
  float q = 0.f;
#pragma unroll
  for (int i = 0; i < 4; ++i) { float d = x[i] - mu; q += d * d; }
  float var = blockReduceSum(q, red) * (1.0f / 1024.0f);
  float rstd = 1.0f / sqrtf(var + 1e-5f);
#pragma unroll
  for (int i = 0; i < 4; ++i) {
    int c = t + i * 256;
    out[r * 1024 + c] = (x[i] - mu) * rstd * g[c] + b[c];
  }
}

// ---------------- gate + bucketing ----------------
__global__ __launch_bounds__(256) void kGate(const float* __restrict__ h1f, const float* __restrict__ gw,
                                             const float* __restrict__ gb,
                                             int2* __restrict__ sel, float2* __restrict__ wgt) {
  const int w = threadIdx.x >> 6, lane = threadIdx.x & 63;
  const long r = (long)blockIdx.x * 4 + w;
  float acc[8] = {0, 0, 0, 0, 0, 0, 0, 0};
  const float* xr = h1f + r * 1024;
  for (int kk = lane; kk < 1024; kk += 64) {
    float x = xr[kk];
    const float* gg = gw + kk * 8;
#pragma unroll
    for (int e = 0; e < 8; ++e) acc[e] += x * gg[e];
  }
#pragma unroll
  for (int e = 0; e < 8; ++e)
    for (int o = 32; o; o >>= 1) acc[e] += __shfl_xor(acc[e], o);
  if (lane == 0) {
    float lg[8];
#pragma unroll
    for (int e = 0; e < 8; ++e) lg[e] = acc[e] + gb[e];
    int e0 = 0; float v0 = lg[0];
#pragma unroll
    for (int e = 1; e < 8; ++e) if (lg[e] > v0) { v0 = lg[e]; e0 = e; }
    int e1 = -1; float v1 = -3e38f;
#pragma unroll
    for (int e = 0; e < 8; ++e) if (e != e0 && lg[e] > v1) { v1 = lg[e]; e1 = e; }
    float ed = expf(v1 - v0);
    float si = 1.0f / (1.0f + ed);
    sel[r] = make_int2(e0, e1);
    wgt[r] = make_float2(si, ed * si);
  }
}

__global__ void kCount(const int2* __restrict__ sel, int* __restrict__ cnt) {
  int r = blockIdx.x * 256 + threadIdx.x;
  if (r < 4096) { int2 s = sel[r]; atomicAdd(&cnt[s.x], 1); atomicAdd(&cnt[s.y], 1); }
}
// 128-aligned per-expert offsets + compact tile map
__global__ void kScan(const int* __restrict__ cnt, int* __restrict__ off,
                      int2* __restrict__ tmap, int* __restrict__ tn) {
  if (threadIdx.x == 0) {
    int run = 0, nt = 0;
    for (int e = 0; e < 8; ++e) {
      off[e] = run;
      int nb = (cnt[e] + 127) >> 7;
      for (int j = 0; j < nb; ++j) { tmap[nt] = make_int2(e, run + (j << 7)); ++nt; }
      run += nb << 7;
    }
    *tn = nt;
  }
}
__global__ void kScatter(const int2* __restrict__ sel, const int* __restrict__ off,
                         int* __restrict__ cur, int* __restrict__ bucket, int2* __restrict__ slotof) {
  int r = blockIdx.x * 256 + threadIdx.x;
  if (r < 4096) {
    int2 s = sel[r];
    int a0 = off[s.x] + atomicAdd(&cur[s.x], 1);
    int a1 = off[s.y] + atomicAdd(&cur[s.y], 1);
    bucket[a0] = r; bucket[a1] = r;
    slotof[r] = make_int2(a0, a1);
  }
}

__global__ __launch_bounds__(256) void kCombine(const float* __restrict__ Z, const int2* __restrict__ slotof,
                                                const float2* __restrict__ wgt, const float* __restrict__ mom_in,
                                                float* __restrict__ mom_out) {
  const long r = blockIdx.x;
  const int t = threadIdx.x;
  int2 sl = slotof[r];
  float2 w = wgt[r];
  const float* z0 = Z + (long)sl.x * 1024;
  const float* z1 = Z + (long)sl.y * 1024;
#pragma unroll
  for (int i = 0; i < 4; ++i) {
    int c = t + i * 256;
    float moe = w.x * z0[c] + w.y * z1[c];
    mom_out[r * 1024 + c] = 0.7f * mom_in[r * 1024 + c] + moe;
  }
}

// ---------------------------------------------------------------------------
extern "C" void kernel_launch(void* const* d_in, const int* in_sizes, int n_in,
                              void* d_out, int out_size, void* d_ws, size_t ws_size,
                              hipStream_t stream) {
  (void)in_sizes; (void)n_in; (void)out_size; (void)ws_size;
  const float* h       = (const float*)d_in[0];
  const float* h_cache = (const float*)d_in[1];
  const float* pos     = (const float*)d_in[2];
  const float* mom_in  = (const float*)d_in[3];
  const float* Wq      = (const float*)d_in[4];
  const float* Wk      = (const float*)d_in[5];
  const float* Wv      = (const float*)d_in[6];
  const float* Wo      = (const float*)d_in[7];
  const float* gate_w  = (const float*)d_in[8];
  const float* gate_b  = (const float*)d_in[9];
  const float* w1      = (const float*)d_in[10];
  const float* b1      = (const float*)d_in[11];
  const float* w2      = (const float*)d_in[12];
  const float* b2      = (const float*)d_in[13];
  const float* ln1g    = (const float*)d_in[14];
  const float* ln1b    = (const float*)d_in[15];
  const float* ln2g    = (const float*)d_in[16];
  const float* ln2b    = (const float*)d_in[17];
  float* out = (float*)d_out;

  char* ws = (char*)d_ws;
  // Phase-aliased region map (total ~391 MB). Lifetimes commented.
  float*          S     = (float*)(ws + 0L);               // ph2 per half
  unsigned short* Y1    = (unsigned short*)(ws + 0L);      // ph5 (9216x4096)
  unsigned short* Oh    = (unsigned short*)(ws + 0L);      // ph3
  unsigned short* Ol    = (unsigned short*)(ws + 8388608L);
  float*          Ppos  = (float*)(ws + 75497472L);        // ph2
  unsigned short* w1T   = (unsigned short*)(ws + 75497472L);   // ph5
  unsigned short* Ph    = (unsigned short*)(ws + 142606336L);  // ph2
  unsigned short* Pl    = (unsigned short*)(ws + 180355072L);
  unsigned short* w2T   = (unsigned short*)(ws + 142606336L);  // ph5
  unsigned short* Xh    = (unsigned short*)(ws + 218103808L);  // ph0-1
  unsigned short* Xl    = (unsigned short*)(ws + 234881024L);
  float*          attnO = (float*)(ws + 218103808L);       // ph2-3 (alias Xh)
  float*          attnWo= (float*)(ws + 234881024L);       // ph3 (alias Xl)
  unsigned short* kh    = (unsigned short*)(ws + 251658240L);  // ph1-2
  unsigned short* kl    = (unsigned short*)(ws + 268435456L);
  float*          h1f   = (float*)(ws + 251658240L);       // ph3+ (alias kh)
  unsigned short* h1h   = (unsigned short*)(ws + 268435456L);  // ph3+ (alias kl)
  unsigned short* VTh   = (unsigned short*)(ws + 285212672L);  // ph1-2
  unsigned short* VTl   = (unsigned short*)(ws + 301989888L);
  unsigned short* qh    = (unsigned short*)(ws + 318767104L);  // ph1-2
  unsigned short* ql    = (unsigned short*)(ws + 327155712L);
  float*          qtmp  = (float*)(ws + 335544320L);       // ph1
  float*          Z     = (float*)(ws + 335544320L);       // ph5-6 (9216x1024)
  unsigned short* WqTh  = (unsigned short*)(ws + 373293056L);
  unsigned short* WqTl  = (unsigned short*)(ws + 375390208L);
  unsigned short* WkTh  = (unsigned short*)(ws + 377487360L);
  unsigned short* WkTl  = (unsigned short*)(ws + 379584512L);
  unsigned short* WvTh  = (unsigned short*)(ws + 381681664L);
  unsigned short* WvTl  = (unsigned short*)(ws + 383778816L);
  unsigned short* WoTh  = (unsigned short*)(ws + 385875968L);
  unsigned short* WoTl  = (unsigned short*)(ws + 387973120L);
  unsigned short* posTh = (unsigned short*)(ws + 390070272L);
  unsigned short* posTl = (unsigned short*)(ws + 390332416L);
  int2*           sel   = (int2*)(ws + 390594560L);
  float2*         wgt   = (float2*)(ws + 390627328L);
  int2*           slotof= (int2*)(ws + 390660096L);
  int*            bucket= (int*)(ws + 390692864L);         // 9216 ints
  int*            cnt   = (int*)(ws + 390729728L);
  int*            cur   = (int*)(ws + 390729760L);
  int*            off   = (int*)(ws + 390729792L);
  int2*           tmap  = (int2*)(ws + 390729856L);        // 80 tiles
  int*            tn    = (int*)(ws + 390730496L);

  // ---- phase 0: concat+split X, transpose+split weights / pos ----
  kConcatSplit<<<8192, 256, 0, stream>>>(h, h_cache, Xh, Xl);
  kTransposeSplit<<<dim3(32, 32, 1), 256, 0, stream>>>(Wq, 0, 1024, 1024, WqTh, WqTl, 0);
  kTransposeSplit<<<dim3(32, 32, 1), 256, 0, stream>>>(Wk, 0, 1024, 1024, WkTh, WkTl, 0);
  kTransposeSplit<<<dim3(32, 32, 1), 256, 0, stream>>>(Wv, 0, 1024, 1024, WvTh, WvTl, 0);
  kTransposeSplit<<<dim3(32, 32, 1), 256, 0, stream>>>(Wo, 0, 1024, 1024, WoTh, WoTl, 0);
  kTransposeSplit<<<dim3(32, 4, 1), 256, 0, stream>>>(pos, 0, 128, 1024, posTh, posTl, 0);

  // ---- phase 1: projections ----
  hipMemsetAsync(qtmp, 0, 16777216L, stream);
  {  // qtmp = h @ Wq (fp32 atomic, K-split 2)
    GemmP p{}; p.zdiv = 1; p.split = 1; p.mode = 5;
    p.Ah = Xh + 1048576; p.Al = Xl + 1048576; p.Bh = WqTh; p.Bl = WqTl;
    p.C = qtmp;
    p.lda = 1024; p.ldb = 1024; p.ldc = 1024; p.K = 1024; p.Kc = 512; p.nx = 8;
    p.a_zo = 2097152; p.c_zo = 1048576; p.c_y = 131072; p.c_x = 128;
    kGemm<<<dim3(16, 8, 4), 256, 0, stream>>>(p);
  }
  kSplitF<<<4096, 256, 0, stream>>>(qtmp, qh, ql, 1048576);
  {  // k = X @ Wk (split store)
    GemmP p{}; p.zdiv = 1; p.split = 1; p.mode = 1;
    p.Ah = Xh; p.Al = Xl; p.Bh = WkTh; p.Bl = WkTl;
    p.C = kh; p.C2 = kl;
    p.lda = 1024; p.ldb = 1024; p.ldc = 1024; p.K = 1024; p.Kc = 1024; p.nx = 8;
    p.c_y = 131072; p.c_x = 128;
    kGemm<<<dim3(8, 64, 1), 256, 0, stream>>>(p);
  }
  {  // VT = (X @ Wv)^T per batch: [b][hd*128+d][key]
    GemmP p{}; p.zdiv = 1; p.split = 1; p.mode = 2;
    p.Ah = Xh; p.Al = Xl; p.Bh = WvTh; p.Bl = WvTl;
    p.C = VTh; p.C2 = VTl;
    p.lda = 1024; p.ldb = 1024; p.ldc = 2048; p.K = 1024; p.Kc = 1024; p.nx = 8;
    p.a_zo = 2097152; p.c_zo = 2097152; p.c_y = 128; p.c_x = 262144;
    kGemm<<<dim3(8, 16, 4), 256, 0, stream>>>(p);
  }

  // ---- phase 2: attention, per batch-half (z = 16 heads) ----
  hipMemsetAsync(attnO, 0, 16777216L, stream);
  for (int hf = 0; hf < 2; ++hf) {
    const long qo = hf * 2097152L, ko = hf * 4194304L, vo = hf * 4194304L;
    {  // Ppos[z][m][l] = q . posT[l]
      GemmP p{}; p.zdiv = 8; p.split = 1; p.mode = 0;
      p.Ah = qh + qo; p.Al = ql + qo; p.Bh = posTh; p.Bl = posTl;
      p.C = Ppos;
      p.lda = 1024; p.ldb = 128; p.ldc = 1024; p.K = 128; p.Kc = 128; p.nx = 8;
      p.a_zo = 1048576; p.a_zi = 128;
      p.c_zo = 8388608; p.c_zi = 1048576; p.c_y = 131072; p.c_x = 128;
      kGemm<<<dim3(8, 8, 16), 256, 0, stream>>>(p);
    }
    {  // banded scores with fused skew lookup + mask + 1/32
      GemmP p{}; p.zdiv = 8; p.split = 1; p.mode = 3;
      p.Ah = qh + qo; p.Al = ql + qo; p.Bh = kh + ko; p.Bl = kl + ko;
      p.C = S; p.xtra = Ppos;
      p.lda = 1024; p.ldb = 1024; p.ldc = 1152; p.xld = 1024; p.K = 128; p.Kc = 128; p.nx = 9;
      p.a_zo = 1048576; p.a_zi = 128;
      p.b_zo = 2097152; p.b_zi = 128; p.b_y = 131072;
      p.c_zo = 9437184; p.c_zi = 1179648; p.c_y = 147456; p.c_x = 128;
      p.x_zo = 8388608; p.x_zi = 1048576; p.x_y = 131072;
      kGemm<<<dim3(9, 8, 16), 256, 0, stream>>>(p);
    }
    kSoftmax<<<16384, 256, 0, stream>>>(S, Ph, Pl);
    {  // attnO += P @ V (K-split 3, fp32 atomic)
      GemmP p{}; p.zdiv = 8; p.split = 1; p.mode = 5;
      p.Ah = Ph; p.Al = Pl; p.Bh = VTh + vo; p.Bl = VTl + vo;
      p.C = attnO + hf * 2097152L;
      p.lda = 1152; p.ldb = 2048; p.ldc = 1024; p.K = 1152; p.Kc = 384; p.nx = 1;
      p.a_zo = 9437184; p.a_zi = 1179648;
      p.b_zo = 2097152; p.b_zi = 262144; p.b_y = 128;
      p.c_zo = 1048576; p.c_zi = 128; p.c_y = 131072; p.c_x = 128;
      kGemm<<<dim3(3, 8, 16), 256, 0, stream>>>(p);
    }
  }

  // ---- phase 3: O split + Wo projection (K-split 2) + LN1 ----
  kSplitF<<<4096, 256, 0, stream>>>(attnO, Oh, Ol, 1048576);
  hipMemsetAsync(attnWo, 0, 16777216L, stream);
  {
    GemmP p{}; p.zdiv = 1; p.split = 1; p.mode = 5;
    p.Ah = Oh; p.Al = Ol; p.Bh = WoTh; p.Bl = WoTl;
    p.C = attnWo;
    p.lda = 1024; p.ldb = 1024; p.ldc = 1024; p.K = 1024; p.Kc = 512; p.nx = 8;
    p.c_y = 131072; p.c_x = 128;
    kGemm<<<dim3(16, 32, 1), 256, 0, stream>>>(p);
  }
  kLN1<<<4096, 256, 0, stream>>>(h, attnWo, ln1g, ln1b, h1f, h1h);

  // ---- phase 4: gate + compact buckets ----
  kGate<<<1024, 256, 0, stream>>>(h1f, gate_w, gate_b, sel, wgt);
  hipMemsetAsync(cnt, 0, 64, stream);              // cnt + cur
  hipMemsetAsync(bucket, 0, 36864, stream);        // pad slots -> row 0
  kCount<<<16, 256, 0, stream>>>(sel, cnt);
  kScan<<<1, 64, 0, stream>>>(cnt, off, tmap, tn);
  kScatter<<<16, 256, 0, stream>>>(sel, off, cur, bucket, slotof);

  // ---- phase 5: MoE (single bf16, compact tile map) ----
  kTransposeSplit<<<dim3(128, 32, 8), 256, 0, stream>>>(w1, 4194304L, 1024, 4096, w1T, nullptr, 4194304L);
  kTransposeSplit<<<dim3(32, 128, 8), 256, 0, stream>>>(w2, 4194304L, 4096, 1024, w2T, nullptr, 4194304L);
  {  // Y1 = relu(gather(h1) @ w1[e] + b1[e])
    GemmP p{}; p.zdiv = 1; p.split = 0; p.mode = 4;
    p.Ah = h1h; p.Bh = w1T;
    p.C = Y1;
    p.idx = bucket; p.tmap = tmap; p.tn = tn;
    p.bias = b1; p.bias_z = 4096;
    p.lda = 1024; p.ldb = 1024; p.ldc = 4096; p.K = 1024; p.Kc = 1024; p.nx = 32;
    p.b_zi = 4194304; p.c_x = 128;
    kGemm<<<dim3(32, 72, 1), 256, 0, stream>>>(p);
  }
  hipMemsetAsync(Z, 0, 37748736L, stream);
  {  // Z += Y1 @ w2[e] + b2[e]  (K-split 2, fp32 atomic)
    GemmP p{}; p.zdiv = 1; p.split = 0; p.mode = 5;
    p.Ah = Y1; p.Bh = w2T;
    p.C = Z;
    p.tmap = tmap; p.tn = tn;
    p.bias = b2; p.bias_z = 1024;
    p.lda = 4096; p.ldb = 4096; p.ldc = 1024; p.K = 4096; p.Kc = 2048; p.nx = 8;
    p.b_zi = 4194304; p.c_x = 128;
    kGemm<<<dim3(16, 72, 1), 256, 0, stream>>>(p);
  }

  // ---- phase 6: combine + momentum + LN2 ----
  float* mom_out = out + 4194304;
  kCombine<<<4096, 256, 0, stream>>>(Z, slotof, wgt, mom_in, mom_out);
  kLN2<<<4096, 256, 0, stream>>>(h1f, mom_out, ln2g, ln2b, out);
}

// Round 4
// 1511.843 us; speedup vs baseline: 1.0917x; 1.0668x over previous
//
#include <hip/hip_runtime.h>

// ---------------------------------------------------------------------------
// TransformerSeqLayer on MI355X.
// Banded (window 1024) rel-pos attention + LN + top-2 MoE + momentum + LN.
// Precision: gate-feeding path uses 2-way bf16-split MFMA (3 MFMAs); MoE
// experts single bf16. This round: template<SPLIT> kGemm; split=0 (MoE) path
// becomes a 2-phase double-buffered K-loop (T3 minimal: prefetch next tile
// BEFORE compute, one barrier/step) reusing the 16KB of LDS that the split
// path needs but split=0 leaves dead -> zero occupancy cost. split=1 GEMMs
// unchanged (in-run control). LDS XOR-swizzle from last round retained
// (bank conflicts measured 0).
// ---------------------------------------------------------------------------

typedef short short8 __attribute__((ext_vector_type(8)));
typedef float f32x4 __attribute__((ext_vector_type(4)));

typedef const void __attribute__((address_space(1)))* gas1_t;
typedef void __attribute__((address_space(3)))* las3_t;
#define ASYNC16(G, L) __builtin_amdgcn_global_load_lds((gas1_t)(G), (las3_t)(L), 16, 0, 0)

#define DEV __device__ __forceinline__

DEV float bf2f(unsigned short u) {
  union { unsigned int u; float f; } x; x.u = ((unsigned int)u) << 16; return x.f;
}
DEV unsigned short f2bf(float f) {
  union { float f; unsigned int u; } x; x.f = f;
  unsigned int r = x.u + 0x7fffu + ((x.u >> 16) & 1u);
  return (unsigned short)(r >> 16);
}

// ---------------------------------------------------------------------------
// Generic 128x128 MFMA GEMM. C[m,n] = sum_k A[m,k]*BT[n,k].
// grid.x = nx * kchunks (bxn = bx%nx selects N-tile, kc = bx/nx selects K chunk
// of length Kc). tmap mode (MoE): by indexes a compact tile list (expert, slot
// base); idx!=null gathers A rows through bucket.
// Modes: 0 fp32+bias store, 1 split-bf16 store, 2 split-bf16 transposed store,
//        3 score epilogue (+Ppos skew lookup, mask, /32), 4 bias+relu+bf16,
//        5 atomicAdd fp32 (+bias only when kc==0).
// LDS tiles are [128][32] shorts with chunk-XOR swizzle: LDS[r][c8] holds
// global chunk c8 ^ ((r>>1)&3). Staging source column is pre-swizzled so
// global_load_lds' linear dest lands data swizzled; fragment reads apply the
// same XOR -> conflict-free ds_read_b128 (verified: SQ_LDS_BANK_CONFLICT=0).
// SPLIT=0: double-buffered 2-phase K-loop (prefetch t+1 before compute t).
// ---------------------------------------------------------------------------
struct GemmP {
  const unsigned short* Ah; const unsigned short* Al;
  const unsigned short* Bh; const unsigned short* Bl;
  void* C; void* C2;
  const float* bias;
  const float* xtra;
  const int* idx; const int2* tmap; const int* tn;
  long a_zo, a_zi;
  long b_zo, b_zi, b_y;
  long c_zo, c_zi, c_y, c_x;
  long x_zo, x_zi, x_y;
  long bias_z;
  int lda, ldb, ldc, xld;
  int K, Kc, nx, zdiv, mode, split;
};

template <int SPLIT>
__global__ __launch_bounds__(256) void kGemm(GemmP p) {
  const int t = threadIdx.x;
  const int bx = blockIdx.x, by = blockIdx.y, bz = blockIdx.z;
  const int zo = bz / p.zdiv, zi = bz % p.zdiv;
  const int bxn = bx % p.nx, kc = bx / p.nx;

  long aOff = 0, bOff, cOff;
  long ar0, ar1;
  int e = zi;
  if (p.tmap) {
    if (by >= *p.tn) return;
    int2 tm = p.tmap[by];
    e = tm.x;
    long base = tm.y;
    cOff = base * p.ldc + (long)bxn * p.c_x;
    bOff = (long)e * p.b_zi + (long)bxn * 128L * p.ldb;
    if (p.idx) { ar0 = p.idx[base + (t >> 2)]; ar1 = p.idx[base + 64 + (t >> 2)]; }
    else { ar0 = base + (t >> 2); ar1 = ar0 + 64; }
  } else {
    aOff = (long)zo * p.a_zo + (long)zi * p.a_zi;
    bOff = (long)zo * p.b_zo + (long)zi * p.b_zi + (long)by * p.b_y + (long)bxn * 128L * p.ldb;
    cOff = (long)zo * p.c_zo + (long)zi * p.c_zi + (long)by * p.c_y + (long)bxn * p.c_x;
    ar0 = by * 128 + (t >> 2); ar1 = ar0 + 64;
  }

  // staging col, XOR-swizzled: chunk (t&3) ^ ((row>>1)&3) with row = t>>2
  const int scol = (((t & 3) ^ ((t >> 3) & 3)) << 3);
  const unsigned short* A0h = p.Ah + aOff + ar0 * (long)p.lda + scol;
  const unsigned short* A1h = p.Ah + aOff + ar1 * (long)p.lda + scol;
  const unsigned short* B0h = p.Bh + bOff + (long)(t >> 2) * p.ldb + scol;
  const unsigned short* B1h = B0h + 64L * p.ldb;
  const unsigned short *A0l = nullptr, *A1l = nullptr, *B0l = nullptr, *B1l = nullptr;
  if (SPLIT) {
    A0l = p.Al + aOff + ar0 * (long)p.lda + scol;
    A1l = p.Al + aOff + ar1 * (long)p.lda + scol;
    B0l = p.Bl + bOff + (long)(t >> 2) * p.ldb + scol;
    B1l = B0l + 64L * p.ldb;
  }

  const int wave = t >> 6;
  const int lane = t & 63;
  const int quad = lane >> 4, l15 = lane & 15;
  const int wr = (wave >> 1) * 64, wc = (wave & 1) * 64;
  // fragment-read chunk, same XOR: quad ^ ((row>>1)&3), row = ...16*i + l15
  const int qs = ((quad ^ ((l15 >> 1) & 3)) << 3);

  f32x4 acc[4][4] = {};
  const int kt0 = (kc * p.Kc) >> 5;
  const int ktN = kt0 + (p.Kc >> 5);

  if constexpr (SPLIT) {
    __shared__ short sAh[4096], sAl[4096], sBh[4096], sBl[4096];
    for (int kt = kt0; kt < ktN; ++kt) {
      const int k0 = kt << 5;
      ASYNC16(A0h + k0, &sAh[wave * 512]);
      ASYNC16(A1h + k0, &sAh[2048 + wave * 512]);
      ASYNC16(B0h + k0, &sBh[wave * 512]);
      ASYNC16(B1h + k0, &sBh[2048 + wave * 512]);
      ASYNC16(A0l + k0, &sAl[wave * 512]);
      ASYNC16(A1l + k0, &sAl[2048 + wave * 512]);
      ASYNC16(B0l + k0, &sBl[wave * 512]);
      ASYNC16(B1l + k0, &sBl[2048 + wave * 512]);
      __syncthreads();
      short8 fa[4], fb[4];
#pragma unroll
      for (int i = 0; i < 4; ++i) {
        fa[i] = *(const short8*)&sAh[(wr + i * 16 + l15) * 32 + qs];
        fb[i] = *(const short8*)&sBh[(wc + i * 16 + l15) * 32 + qs];
      }
#pragma unroll
      for (int bi = 0; bi < 4; ++bi)
#pragma unroll
        for (int bj = 0; bj < 4; ++bj)
          acc[bi][bj] = __builtin_amdgcn_mfma_f32_16x16x32_bf16(fa[bi], fb[bj], acc[bi][bj], 0, 0, 0);
      {
        short8 ga[4], gb[4];
#pragma unroll
        for (int i = 0; i < 4; ++i) {
          ga[i] = *(const short8*)&sAl[(wr + i * 16 + l15) * 32 + qs];
          gb[i] = *(const short8*)&sBl[(wc + i * 16 + l15) * 32 + qs];
        }
#pragma unroll
        for (int bi = 0; bi < 4; ++bi)
#pragma unroll
          for (int bj = 0; bj < 4; ++bj) {
            acc[bi][bj] = __builtin_amdgcn_mfma_f32_16x16x32_bf16(fa[bi], gb[bj], acc[bi][bj], 0, 0, 0);
            acc[bi][bj] = __builtin_amdgcn_mfma_f32_16x16x32_bf16(ga[bi], fb[bj], acc[bi][bj], 0, 0, 0);
          }
      }
      __syncthreads();
    }
  } else {
    // 2-phase double-buffered pipeline: same 32KB LDS as the split path,
    // repurposed as two A/B buffers. One barrier per K-step; next-tile
    // loads issued before current-tile compute so HBM latency hides
    // under ds_read+MFMA (+ TLP across the 5 resident blocks/CU).
    __shared__ short sA[2][4096], sB[2][4096];
    int cur = 0;
    {
      const int k0 = kt0 << 5;
      ASYNC16(A0h + k0, &sA[0][wave * 512]);
      ASYNC16(A1h + k0, &sA[0][2048 + wave * 512]);
      ASYNC16(B0h + k0, &sB[0][wave * 512]);
      ASYNC16(B1h + k0, &sB[0][2048 + wave * 512]);
    }
    __syncthreads();
    for (int kt = kt0; kt < ktN; ++kt) {
      if (kt + 1 < ktN) {
        const int k1 = (kt + 1) << 5;
        ASYNC16(A0h + k1, &sA[cur ^ 1][wave * 512]);
        ASYNC16(A1h + k1, &sA[cur ^ 1][2048 + wave * 512]);
        ASYNC16(B0h + k1, &sB[cur ^ 1][wave * 512]);
        ASYNC16(B1h + k1, &sB[cur ^ 1][2048 + wave * 512]);
      }
      short8 fa[4], fb[4];
#pragma unroll
      for (int i = 0; i < 4; ++i) {
        fa[i] = *(const short8*)&sA[cur][(wr + i * 16 + l15) * 32 + qs];
        fb[i] = *(const short8*)&sB[cur][(wc + i * 16 + l15) * 32 + qs];
      }
#pragma unroll
      for (int bi = 0; bi < 4; ++bi)
#pragma unroll
        for (int bj = 0; bj < 4; ++bj)
          acc[bi][bj] = __builtin_amdgcn_mfma_f32_16x16x32_bf16(fa[bi], fb[bj], acc[bi][bj], 0, 0, 0);
      __syncthreads();   // drains prefetch (vmcnt 0) + protects buffer reuse
      cur ^= 1;
    }
  }

  long xOff = 0;
  if (p.mode == 3) xOff = (long)zo * p.x_zo + (long)zi * p.x_zi + (long)by * p.x_y;
#pragma unroll
  for (int bj = 0; bj < 4; ++bj) {
    const int n_loc = wc + bj * 16 + l15;
    float bv = 0.0f;
    if (p.bias) bv = p.bias[(long)e * p.bias_z + (long)bxn * 128 + n_loc];
#pragma unroll
    for (int bi = 0; bi < 4; ++bi) {
#pragma unroll
      for (int r = 0; r < 4; ++r) {
        const int m_loc = wr + bi * 16 + quad * 4 + r;   // C/D: row=quad*4+reg, col=lane&15
        float v = acc[bi][bj][r];
        if (p.mode == 0) {
          ((float*)p.C)[cOff + (long)m_loc * p.ldc + n_loc] = v + bv;
        } else if (p.mode == 1) {
          long a = cOff + (long)m_loc * p.ldc + n_loc;
          unsigned short hv = f2bf(v);
          ((unsigned short*)p.C)[a] = hv;
          ((unsigned short*)p.C2)[a] = f2bf(v - bf2f(hv));
        } else if (p.mode == 2) {
          long a = cOff + (long)n_loc * p.ldc + m_loc;
          unsigned short hv = f2bf(v);
          ((unsigned short*)p.C)[a] = hv;
          ((unsigned short*)p.C2)[a] = f2bf(v - bf2f(hv));
        } else if (p.mode == 3) {
          int l = bxn * 128 + n_loc - m_loc;
          float outv;
          if ((unsigned)l < 1024u)
            outv = (v + p.xtra[xOff + (long)m_loc * p.xld + l]) * 0.03125f;
          else
            outv = -1e30f;
          ((float*)p.C)[cOff + (long)m_loc * p.ldc + n_loc] = outv;
        } else if (p.mode == 4) {
          float rv = v + bv;
          rv = rv > 0.0f ? rv : 0.0f;
          ((unsigned short*)p.C)[cOff + (long)m_loc * p.ldc + n_loc] = f2bf(rv);
        } else {  // mode 5: atomic fp32 accumulate, bias only in chunk 0
          float av = v + (kc == 0 ? bv : 0.0f);
          atomicAdd(&((float*)p.C)[cOff + (long)m_loc * p.ldc + n_loc], av);
        }
      }
    }
  }
}

// ---------------- prep kernels ----------------
__global__ __launch_bounds__(256) void kConcatSplit(const float* __restrict__ h,
                                                    const float* __restrict__ hc,
                                                    unsigned short* __restrict__ Xh,
                                                    unsigned short* __restrict__ Xl) {
  long i = (((long)blockIdx.x) * 256 + threadIdx.x) * 4;
  long b = i >> 21;
  long rem = i & 2097151;
  const float* s = (rem < 1048576) ? (hc + b * 1048576 + rem) : (h + b * 1048576 + (rem - 1048576));
  f32x4 v = *(const f32x4*)s;
#pragma unroll
  for (int j = 0; j < 4; ++j) {
    float x = v[j];
    unsigned short hi = f2bf(x);
    Xh[i + j] = hi;
    Xl[i + j] = f2bf(x - bf2f(hi));
  }
}

__global__ __launch_bounds__(256) void kTransposeSplit(const float* __restrict__ src, long src_z,
                                                       int R, int C,
                                                       unsigned short* __restrict__ dh,
                                                       unsigned short* __restrict__ dl, long dst_z) {
  __shared__ float tile[32][33];
  const int z = blockIdx.z;
  const float* s = src + (long)z * src_z;
  const int c0 = blockIdx.x * 32, r0 = blockIdx.y * 32;
  const int tx = threadIdx.x & 31, ty = threadIdx.x >> 5;
  for (int i = 0; i < 32; i += 8)
    tile[ty + i][tx] = s[(long)(r0 + ty + i) * C + c0 + tx];
  __syncthreads();
  unsigned short* ph = dh + (long)z * dst_z;
  for (int i = 0; i < 32; i += 8) {
    int c = c0 + ty + i;
    float v = tile[tx][ty + i];
    unsigned short hv = f2bf(v);
    ph[(long)c * R + r0 + tx] = hv;
    if (dl) dl[(long)z * dst_z + (long)c * R + r0 + tx] = f2bf(v - bf2f(hv));
  }
}

// fp32 -> hi/lo bf16 planes
__global__ __launch_bounds__(256) void kSplitF(const float* __restrict__ src,
                                               unsigned short* __restrict__ hi,
                                               unsigned short* __restrict__ lo, int n4) {
  int i = blockIdx.x * 256 + threadIdx.x;
  if (i >= n4) return;
  f32x4 v = ((const f32x4*)src)[i];
#pragma unroll
  for (int j = 0; j < 4; ++j) {
    float x = v[j];
    unsigned short h = f2bf(x);
    hi[i * 4 + j] = h;
    lo[i * 4 + j] = f2bf(x - bf2f(h));
  }
}

// ---------------- softmax over banded score rows (1152 slots) ----------------
__global__ __launch_bounds__(256) void kSoftmax(const float* __restrict__ S,
                                                unsigned short* __restrict__ Ph,
                                                unsigned short* __restrict__ Pl) {
  __shared__ float red[4];
  const long r = blockIdx.x;
  const float* s = S + r * 1152;
  const int t = threadIdx.x;
  float v[5];
  float mx = -3e38f;
#pragma unroll
  for (int i = 0; i < 5; ++i) {
    int c = t + i * 256;
    v[i] = (c < 1152) ? s[c] : -3e38f;
    mx = fmaxf(mx, v[i]);
  }
  for (int o = 32; o; o >>= 1) mx = fmaxf(mx, __shfl_xor(mx, o));
  if ((t & 63) == 0) red[t >> 6] = mx;
  __syncthreads();
  mx = fmaxf(fmaxf(red[0], red[1]), fmaxf(red[2], red[3]));
  __syncthreads();
  float e[5]; float sum = 0.f;
#pragma unroll
  for (int i = 0; i < 5; ++i) {
    int c = t + i * 256;
    e[i] = (c < 1152) ? expf(v[i] - mx) : 0.f;
    sum += e[i];
  }
  for (int o = 32; o; o >>= 1) sum += __shfl_xor(sum, o);
  if ((t & 63) == 0) red[t >> 6] = sum;
  __syncthreads();
  sum = red[0] + red[1] + red[2] + red[3];
  const float inv = 1.0f / sum;
#pragma unroll
  for (int i = 0; i < 5; ++i) {
    int c = t + i * 256;
    if (c < 1152) {
      float pv = e[i] * inv;
      unsigned short hv = f2bf(pv);
      Ph[r * 1152 + c] = hv;
      Pl[r * 1152 + c] = f2bf(pv - bf2f(hv));
    }
  }
}

// ---------------- layernorms ----------------
DEV float blockReduceSum(float v, float* red) {
  for (int o = 32; o; o >>= 1) v += __shfl_xor(v, o);
  if ((threadIdx.x & 63) == 0) red[threadIdx.x >> 6] = v;
  __syncthreads();
  v = red[0] + red[1] + red[2] + red[3];
  __syncthreads();
  return v;
}

__global__ __launch_bounds__(256) void kLN1(const float* __restrict__ h, const float* __restrict__ aw,
                                            const float* __restrict__ g, const float* __restrict__ b,
                                            float* __restrict__ h1f, unsigned short* __restrict__ h1h) {
  __shared__ float red[4];
  const long r = blockIdx.x;
  const int t = threadIdx.x;
  float x[4]; float s = 0.f;
#pragma unroll
  for (int i = 0; i < 4; ++i) { int c = t + i * 256; x[i] = h[r * 1024 + c] + aw[r * 1024 + c]; s += x[i]; }
  float mu = blockReduceSum(s, red) * (1.0f / 1024.0f);
  float q = 0.f;
#pragma unroll
  for (int i = 0; i < 4; ++i) { float d = x[i] - mu; q += d * d; }
  float var = blockReduceSum(q, red) * (1.0f / 1024.0f);
  float rstd = 1.0f / sqrtf(var + 1e-5f);
#pragma unroll
  for (int i = 0; i < 4; ++i) {
    int c = t + i * 256;
    float y = (x[i] - mu) * rstd * g[c] + b[c];
    h1f[r * 1024 + c] = y;
    h1h[r * 1024 + c] = f2bf(y);
  }
}

__global__ __launch_bounds__(256) void kLN2(const float* __restrict__ h1f, const float* __restrict__ mom,
                                            const float* __restrict__ g, const float* __restrict__ b,
                                            float* __restrict__ out) {
  __shared__ float red[4];
  const long r = blockIdx.x;
  const int t = threadIdx.x;
  float x[4]; float s = 0.f;
#pragma unroll
  for (int i = 0; i < 4; ++i) { int c = t + i * 256; x[i] = h1f[r * 1024 + c] - mom[r * 1024 + c]; s += x[i]; }
  float mu = blockReduceSum(s, red) * (1.0f / 1024.0f);
  float q = 0.f;
#pragma unroll
  for (int i = 0; i < 4; ++i) { float d = x[i] - mu; q += d * d; }
  float var = blockReduceSum(q, red) * (1.0f / 1024.0f);
  float rstd = 1.0f / sqrtf(var + 1e-5f);
#pragma unroll
  for (int i = 0; i < 4; ++i) {
    int c = t + i * 256;
    out[r * 1024 + c] = (x[i] - mu) * rstd * g[c] + b[c];
  }
}

// ---------------- gate + bucketing ----------------
__global__ __launch_bounds__(256) void kGate(const float* __restrict__ h1f, const float* __restrict__ gw,
                                             const float* __restrict__ gb,
                                             int2* __restrict__ sel, float2* __restrict__ wgt) {
  const int w = threadIdx.x >> 6, lane = threadIdx.x & 63;
  const long r = (long)blockIdx.x * 4 + w;
  float acc[8] = {0, 0, 0, 0, 0, 0, 0, 0};
  const float* xr = h1f + r * 1024;
  for (int kk = lane; kk < 1024; kk += 64) {
    float x = xr[kk];
    const float* gg = gw + kk * 8;
#pragma unroll
    for (int e = 0; e < 8; ++e) acc[e] += x * gg[e];
  }
#pragma unroll
  for (int e = 0; e < 8; ++e)
    for (int o = 32; o; o >>= 1) acc[e] += __shfl_xor(acc[e], o);
  if (lane == 0) {
    float lg[8];
#pragma unroll
    for (int e = 0; e < 8; ++e) lg[e] = acc[e] + gb[e];
    int e0 = 0; float v0 = lg[0];
#pragma unroll
    for (int e = 1; e < 8; ++e) if (lg[e] > v0) { v0 = lg[e]; e0 = e; }
    int e1 = -1; float v1 = -3e38f;
#pragma unroll
    for (int e = 0; e < 8; ++e) if (e != e0 && lg[e] > v1) { v1 = lg[e]; e1 = e; }
    float ed = expf(v1 - v0);
    float si = 1.0f / (1.0f + ed);
    sel[r] = make_int2(e0, e1);
    wgt[r] = make_float2(si, ed * si);
  }
}

__global__ void kCount(const int2* __restrict__ sel, int* __restrict__ cnt) {
  int r = blockIdx.x * 256 + threadIdx.x;
  if (r < 4096) { int2 s = sel[r]; atomicAdd(&cnt[s.x], 1); atomicAdd(&cnt[s.y], 1); }
}
// 128-aligned per-expert offsets + compact tile map
__global__ void kScan(const int* __restrict__ cnt, int* __restrict__ off,
                      int2* __restrict__ tmap, int* __restrict__ tn) {
  if (threadIdx.x == 0) {
    int run = 0, nt = 0;
    for (int e = 0; e < 8; ++e) {
      off[e] = run;
      int nb = (cnt[e] + 127) >> 7;
      for (int j = 0; j < nb; ++j) { tmap[nt] = make_int2(e, run + (j << 7)); ++nt; }
      run += nb << 7;
    }
    *tn = nt;
  }
}
__global__ void kScatter(const int2* __restrict__ sel, const int* __restrict__ off,
                         int* __restrict__ cur, int* __restrict__ bucket, int2* __restrict__ slotof) {
  int r = blockIdx.x * 256 + threadIdx.x;
  if (r < 4096) {
    int2 s = sel[r];
    int a0 = off[s.x] + atomicAdd(&cur[s.x], 1);
    int a1 = off[s.y] + atomicAdd(&cur[s.y], 1);
    bucket[a0] = r; bucket[a1] = r;
    slotof[r] = make_int2(a0, a1);
  }
}

__global__ __launch_bounds__(256) void kCombine(const float* __restrict__ Z, const int2* __restrict__ slotof,
                                                const float2* __restrict__ wgt, const float* __restrict__ mom_in,
                                                float* __restrict__ mom_out) {
  const long r = blockIdx.x;
  const int t = threadIdx.x;
  int2 sl = slotof[r];
  float2 w = wgt[r];
  const float* z0 = Z + (long)sl.x * 1024;
  const float* z1 = Z + (long)sl.y * 1024;
#pragma unroll
  for (int i = 0; i < 4; ++i) {
    int c = t + i * 256;
    float moe = w.x * z0[c] + w.y * z1[c];
    mom_out[r * 1024 + c] = 0.7f * mom_in[r * 1024 + c] + moe;
  }
}

// ---------------------------------------------------------------------------
extern "C" void kernel_launch(void* const* d_in, const int* in_sizes, int n_in,
                              void* d_out, int out_size, void* d_ws, size_t ws_size,
                              hipStream_t stream) {
  (void)in_sizes; (void)n_in; (void)out_size; (void)ws_size;
  const float* h       = (const float*)d_in[0];
  const float* h_cache = (const float*)d_in[1];
  const float* pos     = (const float*)d_in[2];
  const float* mom_in  = (const float*)d_in[3];
  const float* Wq      = (const float*)d_in[4];
  const float* Wk      = (const float*)d_in[5];
  const float* Wv      = (const float*)d_in[6];
  const float* Wo      = (const float*)d_in[7];
  const float* gate_w  = (const float*)d_in[8];
  const float* gate_b  = (const float*)d_in[9];
  const float* w1      = (const float*)d_in[10];
  const float* b1      = (const float*)d_in[11];
  const float* w2      = (const float*)d_in[12];
  const float* b2      = (const float*)d_in[13];
  const float* ln1g    = (const float*)d_in[14];
  const float* ln1b    = (const float*)d_in[15];
  const float* ln2g    = (const float*)d_in[16];
  const float* ln2b    = (const float*)d_in[17];
  float* out = (float*)d_out;

  char* ws = (char*)d_ws;
  // Phase-aliased region map (total ~391 MB). Lifetimes commented.
  float*          S     = (float*)(ws + 0L);               // ph2 per half
  unsigned short* Y1    = (unsigned short*)(ws + 0L);      // ph5 (9216x4096)
  unsigned short* Oh    = (unsigned short*)(ws + 0L);      // ph3
  unsigned short* Ol    = (unsigned short*)(ws + 8388608L);
  float*          Ppos  = (float*)(ws + 75497472L);        // ph2
  unsigned short* w1T   = (unsigned short*)(ws + 75497472L);   // ph5
  unsigned short* Ph    = (unsigned short*)(ws + 142606336L);  // ph2
  unsigned short* Pl    = (unsigned short*)(ws + 180355072L);
  unsigned short* w2T   = (unsigned short*)(ws + 142606336L);  // ph5
  unsigned short* Xh    = (unsigned short*)(ws + 218103808L);  // ph0-1
  unsigned short* Xl    = (unsigned short*)(ws + 234881024L);
  float*          attnO = (float*)(ws + 218103808L);       // ph2-3 (alias Xh)
  float*          attnWo= (float*)(ws + 234881024L);       // ph3 (alias Xl)
  unsigned short* kh    = (unsigned short*)(ws + 251658240L);  // ph1-2
  unsigned short* kl    = (unsigned short*)(ws + 268435456L);
  float*          h1f   = (float*)(ws + 251658240L);       // ph3+ (alias kh)
  unsigned short* h1h   = (unsigned short*)(ws + 268435456L);  // ph3+ (alias kl)
  unsigned short* VTh   = (unsigned short*)(ws + 285212672L);  // ph1-2
  unsigned short* VTl   = (unsigned short*)(ws + 301989888L);
  unsigned short* qh    = (unsigned short*)(ws + 318767104L);  // ph1-2
  unsigned short* ql    = (unsigned short*)(ws + 327155712L);
  float*          qtmp  = (float*)(ws + 335544320L);       // ph1
  float*          Z     = (float*)(ws + 335544320L);       // ph5-6 (9216x1024)
  unsigned short* WqTh  = (unsigned short*)(ws + 373293056L);
  unsigned short* WqTl  = (unsigned short*)(ws + 375390208L);
  unsigned short* WkTh  = (unsigned short*)(ws + 377487360L);
  unsigned short* WkTl  = (unsigned short*)(ws + 379584512L);
  unsigned short* WvTh  = (unsigned short*)(ws + 381681664L);
  unsigned short* WvTl  = (unsigned short*)(ws + 383778816L);
  unsigned short* WoTh  = (unsigned short*)(ws + 385875968L);
  unsigned short* WoTl  = (unsigned short*)(ws + 387973120L);
  unsigned short* posTh = (unsigned short*)(ws + 390070272L);
  unsigned short* posTl = (unsigned short*)(ws + 390332416L);
  int2*           sel   = (int2*)(ws + 390594560L);
  float2*         wgt   = (float2*)(ws + 390627328L);
  int2*           slotof= (int2*)(ws + 390660096L);
  int*            bucket= (int*)(ws + 390692864L);         // 9216 ints
  int*            cnt   = (int*)(ws + 390729728L);
  int*            cur   = (int*)(ws + 390729760L);
  int*            off   = (int*)(ws + 390729792L);
  int2*           tmap  = (int2*)(ws + 390729856L);        // 80 tiles
  int*            tn    = (int*)(ws + 390730496L);

  // ---- phase 0: concat+split X, transpose+split weights / pos ----
  kConcatSplit<<<8192, 256, 0, stream>>>(h, h_cache, Xh, Xl);
  kTransposeSplit<<<dim3(32, 32, 1), 256, 0, stream>>>(Wq, 0, 1024, 1024, WqTh, WqTl, 0);
  kTransposeSplit<<<dim3(32, 32, 1), 256, 0, stream>>>(Wk, 0, 1024, 1024, WkTh, WkTl, 0);
  kTransposeSplit<<<dim3(32, 32, 1), 256, 0, stream>>>(Wv, 0, 1024, 1024, WvTh, WvTl, 0);
  kTransposeSplit<<<dim3(32, 32, 1), 256, 0, stream>>>(Wo, 0, 1024, 1024, WoTh, WoTl, 0);
  kTransposeSplit<<<dim3(32, 4, 1), 256, 0, stream>>>(pos, 0, 128, 1024, posTh, posTl, 0);

  // ---- phase 1: projections ----
  hipMemsetAsync(qtmp, 0, 16777216L, stream);
  {  // qtmp = h @ Wq (fp32 atomic, K-split 2)
    GemmP p{}; p.zdiv = 1; p.split = 1; p.mode = 5;
    p.Ah = Xh + 1048576; p.Al = Xl + 1048576; p.Bh = WqTh; p.Bl = WqTl;
    p.C = qtmp;
    p.lda = 1024; p.ldb = 1024; p.ldc = 1024; p.K = 1024; p.Kc = 512; p.nx = 8;
    p.a_zo = 2097152; p.c_zo = 1048576; p.c_y = 131072; p.c_x = 128;
    kGemm<1><<<dim3(16, 8, 4), 256, 0, stream>>>(p);
  }
  kSplitF<<<4096, 256, 0, stream>>>(qtmp, qh, ql, 1048576);
  {  // k = X @ Wk (split store)
    GemmP p{}; p.zdiv = 1; p.split = 1; p.mode = 1;
    p.Ah = Xh; p.Al = Xl; p.Bh = WkTh; p.Bl = WkTl;
    p.C = kh; p.C2 = kl;
    p.lda = 1024; p.ldb = 1024; p.ldc = 1024; p.K = 1024; p.Kc = 1024; p.nx = 8;
    p.c_y = 131072; p.c_x = 128;
    kGemm<1><<<dim3(8, 64, 1), 256, 0, stream>>>(p);
  }
  {  // VT = (X @ Wv)^T per batch: [b][hd*128+d][key]
    GemmP p{}; p.zdiv = 1; p.split = 1; p.mode = 2;
    p.Ah = Xh; p.Al = Xl; p.Bh = WvTh; p.Bl = WvTl;
    p.C = VTh; p.C2 = VTl;
    p.lda = 1024; p.ldb = 1024; p.ldc = 2048; p.K = 1024; p.Kc = 1024; p.nx = 8;
    p.a_zo = 2097152; p.c_zo = 2097152; p.c_y = 128; p.c_x = 262144;
    kGemm<1><<<dim3(8, 16, 4), 256, 0, stream>>>(p);
  }

  // ---- phase 2: attention, per batch-half (z = 16 heads) ----
  hipMemsetAsync(attnO, 0, 16777216L, stream);
  for (int hf = 0; hf < 2; ++hf) {
    const long qo = hf * 2097152L, ko = hf * 4194304L, vo = hf * 4194304L;
    {  // Ppos[z][m][l] = q . posT[l]
      GemmP p{}; p.zdiv = 8; p.split = 1; p.mode = 0;
      p.Ah = qh + qo; p.Al = ql + qo; p.Bh = posTh; p.Bl = posTl;
      p.C = Ppos;
      p.lda = 1024; p.ldb = 128; p.ldc = 1024; p.K = 128; p.Kc = 128; p.nx = 8;
      p.a_zo = 1048576; p.a_zi = 128;
      p.c_zo = 8388608; p.c_zi = 1048576; p.c_y = 131072; p.c_x = 128;
      kGemm<1><<<dim3(8, 8, 16), 256, 0, stream>>>(p);
    }
    {  // banded scores with fused skew lookup + mask + 1/32
      GemmP p{}; p.zdiv = 8; p.split = 1; p.mode = 3;
      p.Ah = qh + qo; p.Al = ql + qo; p.Bh = kh + ko; p.Bl = kl + ko;
      p.C = S; p.xtra = Ppos;
      p.lda = 1024; p.ldb = 1024; p.ldc = 1152; p.xld = 1024; p.K = 128; p.Kc = 128; p.nx = 9;
      p.a_zo = 1048576; p.a_zi = 128;
      p.b_zo = 2097152; p.b_zi = 128; p.b_y = 131072;
      p.c_zo = 9437184; p.c_zi = 1179648; p.c_y = 147456; p.c_x = 128;
      p.x_zo = 8388608; p.x_zi = 1048576; p.x_y = 131072;
      kGemm<1><<<dim3(9, 8, 16), 256, 0, stream>>>(p);
    }
    kSoftmax<<<16384, 256, 0, stream>>>(S, Ph, Pl);
    {  // attnO += P @ V (K-split 3, fp32 atomic)
      GemmP p{}; p.zdiv = 8; p.split = 1; p.mode = 5;
      p.Ah = Ph; p.Al = Pl; p.Bh = VTh + vo; p.Bl = VTl + vo;
      p.C = attnO + hf * 2097152L;
      p.lda = 1152; p.ldb = 2048; p.ldc = 1024; p.K = 1152; p.Kc = 384; p.nx = 1;
      p.a_zo = 9437184; p.a_zi = 1179648;
      p.b_zo = 2097152; p.b_zi = 262144; p.b_y = 128;
      p.c_zo = 1048576; p.c_zi = 128; p.c_y = 131072; p.c_x = 128;
      kGemm<1><<<dim3(3, 8, 16), 256, 0, stream>>>(p);
    }
  }

  // ---- phase 3: O split + Wo projection (K-split 2) + LN1 ----
  kSplitF<<<4096, 256, 0, stream>>>(attnO, Oh, Ol, 1048576);
  hipMemsetAsync(attnWo, 0, 16777216L, stream);
  {
    GemmP p{}; p.zdiv = 1; p.split = 1; p.mode = 5;
    p.Ah = Oh; p.Al = Ol; p.Bh = WoTh; p.Bl = WoTl;
    p.C = attnWo;
    p.lda = 1024; p.ldb = 1024; p.ldc = 1024; p.K = 1024; p.Kc = 512; p.nx = 8;
    p.c_y = 131072; p.c_x = 128;
    kGemm<1><<<dim3(16, 32, 1), 256, 0, stream>>>(p);
  }
  kLN1<<<4096, 256, 0, stream>>>(h, attnWo, ln1g, ln1b, h1f, h1h);

  // ---- phase 4: gate + compact buckets ----
  kGate<<<1024, 256, 0, stream>>>(h1f, gate_w, gate_b, sel, wgt);
  hipMemsetAsync(cnt, 0, 64, stream);              // cnt + cur
  hipMemsetAsync(bucket, 0, 36864, stream);        // pad slots -> row 0
  kCount<<<16, 256, 0, stream>>>(sel, cnt);
  kScan<<<1, 64, 0, stream>>>(cnt, off, tmap, tn);
  kScatter<<<16, 256, 0, stream>>>(sel, off, cur, bucket, slotof);

  // ---- phase 5: MoE (single bf16, compact tile map, 2-phase dbuf) ----
  kTransposeSplit<<<dim3(128, 32, 8), 256, 0, stream>>>(w1, 4194304L, 1024, 4096, w1T, nullptr, 4194304L);
  kTransposeSplit<<<dim3(32, 128, 8), 256, 0, stream>>>(w2, 4194304L, 4096, 1024, w2T, nullptr, 4194304L);
  {  // Y1 = relu(gather(h1) @ w1[e] + b1[e])
    GemmP p{}; p.zdiv = 1; p.split = 0; p.mode = 4;
    p.Ah = h1h; p.Bh = w1T;
    p.C = Y1;
    p.idx = bucket; p.tmap = tmap; p.tn = tn;
    p.bias = b1; p.bias_z = 4096;
    p.lda = 1024; p.ldb = 1024; p.ldc = 4096; p.K = 1024; p.Kc = 1024; p.nx = 32;
    p.b_zi = 4194304; p.c_x = 128;
    kGemm<0><<<dim3(32, 72, 1), 256, 0, stream>>>(p);
  }
  hipMemsetAsync(Z, 0, 37748736L, stream);
  {  // Z += Y1 @ w2[e] + b2[e]  (K-split 2, fp32 atomic)
    GemmP p{}; p.zdiv = 1; p.split = 0; p.mode = 5;
    p.Ah = Y1; p.Bh = w2T;
    p.C = Z;
    p.tmap = tmap; p.tn = tn;
    p.bias = b2; p.bias_z = 1024;
    p.lda = 4096; p.ldb = 4096; p.ldc = 1024; p.K = 4096; p.Kc = 2048; p.nx = 8;
    p.b_zi = 4194304; p.c_x = 128;
    kGemm<0><<<dim3(16, 72, 1), 256, 0, stream>>>(p);
  }

  // ---- phase 6: combine + momentum + LN2 ----
  float* mom_out = out + 4194304;
  kCombine<<<4096, 256, 0, stream>>>(Z, slotof, wgt, mom_in, mom_out);
  kLN2<<<4096, 256, 0, stream>>>(h1f, mom_out, ln2g, ln2b, out);
}

// Round 5
// 1502.175 us; speedup vs baseline: 1.0987x; 1.0064x over previous
//
#include <hip/hip_runtime.h>

// ---------------------------------------------------------------------------
// TransformerSeqLayer on MI355X.
// Banded (window 1024) rel-pos attention + LN + top-2 MoE + momentum + LN.
// Precision: gate-feeding path uses 2-way bf16-split MFMA (3 MFMAs); MoE
// experts single bf16. This round: SPLIT=0 (MoE) K-loop upgraded from
// drain-0 __syncthreads to counted-vmcnt pipeline (T4): prefetch next tile,
// s_waitcnt vmcnt(4) (next-tile loads stay in flight across the barrier),
// raw s_barrier, ds_read+MFMA, raw s_barrier (buffer-reuse fence). Old
// buffer's loads get a full iteration of latency hiding instead of zero.
// split=1 GEMMs unchanged (in-run control). XOR-swizzle retained (conflicts=0).
// ---------------------------------------------------------------------------

typedef short short8 __attribute__((ext_vector_type(8)));
typedef float f32x4 __attribute__((ext_vector_type(4)));

typedef const void __attribute__((address_space(1)))* gas1_t;
typedef void __attribute__((address_space(3)))* las3_t;
#define ASYNC16(G, L) __builtin_amdgcn_global_load_lds((gas1_t)(G), (las3_t)(L), 16, 0, 0)

#define DEV __device__ __forceinline__

DEV float bf2f(unsigned short u) {
  union { unsigned int u; float f; } x; x.u = ((unsigned int)u) << 16; return x.f;
}
DEV unsigned short f2bf(float f) {
  union { float f; unsigned int u; } x; x.f = f;
  unsigned int r = x.u + 0x7fffu + ((x.u >> 16) & 1u);
  return (unsigned short)(r >> 16);
}

// ---------------------------------------------------------------------------
// Generic 128x128 MFMA GEMM. C[m,n] = sum_k A[m,k]*BT[n,k].
// grid.x = nx * kchunks (bxn = bx%nx selects N-tile, kc = bx/nx selects K chunk
// of length Kc). tmap mode (MoE): by indexes a compact tile list (expert, slot
// base); idx!=null gathers A rows through bucket.
// Modes: 0 fp32+bias store, 1 split-bf16 store, 2 split-bf16 transposed store,
//        3 score epilogue (+Ppos skew lookup, mask, /32), 4 bias+relu+bf16,
//        5 atomicAdd fp32 (+bias only when kc==0).
// LDS tiles are [128][32] shorts with chunk-XOR swizzle: LDS[r][c8] holds
// global chunk c8 ^ ((r>>1)&3). Staging source column is pre-swizzled so
// global_load_lds' linear dest lands data swizzled; fragment reads apply the
// same XOR -> conflict-free ds_read_b128 (verified: SQ_LDS_BANK_CONFLICT=0).
// SPLIT=0: 2-buffer counted-vmcnt pipeline:
//   STAGE(nxt); vmcnt(4); s_barrier; ds_read+MFMA(cur); s_barrier; swap.
// vmcnt(4) leaves the 4 just-issued next-tile loads in flight; the trailing
// barrier (after lgkm-retired ds_reads) fences buffer reuse.
// ---------------------------------------------------------------------------
struct GemmP {
  const unsigned short* Ah; const unsigned short* Al;
  const unsigned short* Bh; const unsigned short* Bl;
  void* C; void* C2;
  const float* bias;
  const float* xtra;
  const int* idx; const int2* tmap; const int* tn;
  long a_zo, a_zi;
  long b_zo, b_zi, b_y;
  long c_zo, c_zi, c_y, c_x;
  long x_zo, x_zi, x_y;
  long bias_z;
  int lda, ldb, ldc, xld;
  int K, Kc, nx, zdiv, mode, split;
};

template <int SPLIT>
__global__ __launch_bounds__(256) void kGemm(GemmP p) {
  const int t = threadIdx.x;
  const int bx = blockIdx.x, by = blockIdx.y, bz = blockIdx.z;
  const int zo = bz / p.zdiv, zi = bz % p.zdiv;
  const int bxn = bx % p.nx, kc = bx / p.nx;

  long aOff = 0, bOff, cOff;
  long ar0, ar1;
  int e = zi;
  if (p.tmap) {
    if (by >= *p.tn) return;
    int2 tm = p.tmap[by];
    e = tm.x;
    long base = tm.y;
    cOff = base * p.ldc + (long)bxn * p.c_x;
    bOff = (long)e * p.b_zi + (long)bxn * 128L * p.ldb;
    if (p.idx) { ar0 = p.idx[base + (t >> 2)]; ar1 = p.idx[base + 64 + (t >> 2)]; }
    else { ar0 = base + (t >> 2); ar1 = ar0 + 64; }
  } else {
    aOff = (long)zo * p.a_zo + (long)zi * p.a_zi;
    bOff = (long)zo * p.b_zo + (long)zi * p.b_zi + (long)by * p.b_y + (long)bxn * 128L * p.ldb;
    cOff = (long)zo * p.c_zo + (long)zi * p.c_zi + (long)by * p.c_y + (long)bxn * p.c_x;
    ar0 = by * 128 + (t >> 2); ar1 = ar0 + 64;
  }

  // staging col, XOR-swizzled: chunk (t&3) ^ ((row>>1)&3) with row = t>>2
  const int scol = (((t & 3) ^ ((t >> 3) & 3)) << 3);
  const unsigned short* A0h = p.Ah + aOff + ar0 * (long)p.lda + scol;
  const unsigned short* A1h = p.Ah + aOff + ar1 * (long)p.lda + scol;
  const unsigned short* B0h = p.Bh + bOff + (long)(t >> 2) * p.ldb + scol;
  const unsigned short* B1h = B0h + 64L * p.ldb;
  const unsigned short *A0l = nullptr, *A1l = nullptr, *B0l = nullptr, *B1l = nullptr;
  if (SPLIT) {
    A0l = p.Al + aOff + ar0 * (long)p.lda + scol;
    A1l = p.Al + aOff + ar1 * (long)p.lda + scol;
    B0l = p.Bl + bOff + (long)(t >> 2) * p.ldb + scol;
    B1l = B0l + 64L * p.ldb;
  }

  const int wave = t >> 6;
  const int lane = t & 63;
  const int quad = lane >> 4, l15 = lane & 15;
  const int wr = (wave >> 1) * 64, wc = (wave & 1) * 64;
  // fragment-read chunk, same XOR: quad ^ ((row>>1)&3), row = ...16*i + l15
  const int qs = ((quad ^ ((l15 >> 1) & 3)) << 3);

  f32x4 acc[4][4] = {};
  const int kt0 = (kc * p.Kc) >> 5;
  const int ktN = kt0 + (p.Kc >> 5);

  if constexpr (SPLIT) {
    __shared__ short sAh[4096], sAl[4096], sBh[4096], sBl[4096];
    for (int kt = kt0; kt < ktN; ++kt) {
      const int k0 = kt << 5;
      ASYNC16(A0h + k0, &sAh[wave * 512]);
      ASYNC16(A1h + k0, &sAh[2048 + wave * 512]);
      ASYNC16(B0h + k0, &sBh[wave * 512]);
      ASYNC16(B1h + k0, &sBh[2048 + wave * 512]);
      ASYNC16(A0l + k0, &sAl[wave * 512]);
      ASYNC16(A1l + k0, &sAl[2048 + wave * 512]);
      ASYNC16(B0l + k0, &sBl[wave * 512]);
      ASYNC16(B1l + k0, &sBl[2048 + wave * 512]);
      __syncthreads();
      short8 fa[4], fb[4];
#pragma unroll
      for (int i = 0; i < 4; ++i) {
        fa[i] = *(const short8*)&sAh[(wr + i * 16 + l15) * 32 + qs];
        fb[i] = *(const short8*)&sBh[(wc + i * 16 + l15) * 32 + qs];
      }
#pragma unroll
      for (int bi = 0; bi < 4; ++bi)
#pragma unroll
        for (int bj = 0; bj < 4; ++bj)
          acc[bi][bj] = __builtin_amdgcn_mfma_f32_16x16x32_bf16(fa[bi], fb[bj], acc[bi][bj], 0, 0, 0);
      {
        short8 ga[4], gb[4];
#pragma unroll
        for (int i = 0; i < 4; ++i) {
          ga[i] = *(const short8*)&sAl[(wr + i * 16 + l15) * 32 + qs];
          gb[i] = *(const short8*)&sBl[(wc + i * 16 + l15) * 32 + qs];
        }
#pragma unroll
        for (int bi = 0; bi < 4; ++bi)
#pragma unroll
          for (int bj = 0; bj < 4; ++bj) {
            acc[bi][bj] = __builtin_amdgcn_mfma_f32_16x16x32_bf16(fa[bi], gb[bj], acc[bi][bj], 0, 0, 0);
            acc[bi][bj] = __builtin_amdgcn_mfma_f32_16x16x32_bf16(ga[bi], fb[bj], acc[bi][bj], 0, 0, 0);
          }
      }
      __syncthreads();
    }
  } else {
    // Counted-vmcnt 2-buffer pipeline (T4). Per iter: issue next-tile loads,
    // wait vmcnt(4) (old buffer's loads done; the 4 new stay in flight),
    // raw barrier, ds_read+MFMA current, raw barrier (buffer-reuse fence —
    // ds_reads are lgkm-retired before MFMA issue, so reads are complete).
    __shared__ short sA[2][4096], sB[2][4096];
    int cur = 0;
    {
      const int k0 = kt0 << 5;
      ASYNC16(A0h + k0, &sA[0][wave * 512]);
      ASYNC16(A1h + k0, &sA[0][2048 + wave * 512]);
      ASYNC16(B0h + k0, &sB[0][wave * 512]);
      ASYNC16(B1h + k0, &sB[0][2048 + wave * 512]);
    }
    for (int kt = kt0; kt < ktN; ++kt) {
      if (kt + 1 < ktN) {
        const int k1 = (kt + 1) << 5;
        ASYNC16(A0h + k1, &sA[cur ^ 1][wave * 512]);
        ASYNC16(A1h + k1, &sA[cur ^ 1][2048 + wave * 512]);
        ASYNC16(B0h + k1, &sB[cur ^ 1][wave * 512]);
        ASYNC16(B1h + k1, &sB[cur ^ 1][2048 + wave * 512]);
        asm volatile("s_waitcnt vmcnt(4)" ::: "memory");
      } else {
        asm volatile("s_waitcnt vmcnt(0)" ::: "memory");
      }
      __builtin_amdgcn_s_barrier();
      short8 fa[4], fb[4];
#pragma unroll
      for (int i = 0; i < 4; ++i) {
        fa[i] = *(const short8*)&sA[cur][(wr + i * 16 + l15) * 32 + qs];
        fb[i] = *(const short8*)&sB[cur][(wc + i * 16 + l15) * 32 + qs];
      }
#pragma unroll
      for (int bi = 0; bi < 4; ++bi)
#pragma unroll
        for (int bj = 0; bj < 4; ++bj)
          acc[bi][bj] = __builtin_amdgcn_mfma_f32_16x16x32_bf16(fa[bi], fb[bj], acc[bi][bj], 0, 0, 0);
      __builtin_amdgcn_s_barrier();
      cur ^= 1;
    }
  }

  long xOff = 0;
  if (p.mode == 3) xOff = (long)zo * p.x_zo + (long)zi * p.x_zi + (long)by * p.x_y;
#pragma unroll
  for (int bj = 0; bj < 4; ++bj) {
    const int n_loc = wc + bj * 16 + l15;
    float bv = 0.0f;
    if (p.bias) bv = p.bias[(long)e * p.bias_z + (long)bxn * 128 + n_loc];
#pragma unroll
    for (int bi = 0; bi < 4; ++bi) {
#pragma unroll
      for (int r = 0; r < 4; ++r) {
        const int m_loc = wr + bi * 16 + quad * 4 + r;   // C/D: row=quad*4+reg, col=lane&15
        float v = acc[bi][bj][r];
        if (p.mode == 0) {
          ((float*)p.C)[cOff + (long)m_loc * p.ldc + n_loc] = v + bv;
        } else if (p.mode == 1) {
          long a = cOff + (long)m_loc * p.ldc + n_loc;
          unsigned short hv = f2bf(v);
          ((unsigned short*)p.C)[a] = hv;
          ((unsigned short*)p.C2)[a] = f2bf(v - bf2f(hv));
        } else if (p.mode == 2) {
          long a = cOff + (long)n_loc * p.ldc + m_loc;
          unsigned short hv = f2bf(v);
          ((unsigned short*)p.C)[a] = hv;
          ((unsigned short*)p.C2)[a] = f2bf(v - bf2f(hv));
        } else if (p.mode == 3) {
          int l = bxn * 128 + n_loc - m_loc;
          float outv;
          if ((unsigned)l < 1024u)
            outv = (v + p.xtra[xOff + (long)m_loc * p.xld + l]) * 0.03125f;
          else
            outv = -1e30f;
          ((float*)p.C)[cOff + (long)m_loc * p.ldc + n_loc] = outv;
        } else if (p.mode == 4) {
          float rv = v + bv;
          rv = rv > 0.0f ? rv : 0.0f;
          ((unsigned short*)p.C)[cOff + (long)m_loc * p.ldc + n_loc] = f2bf(rv);
        } else {  // mode 5: atomic fp32 accumulate, bias only in chunk 0
          float av = v + (kc == 0 ? bv : 0.0f);
          atomicAdd(&((float*)p.C)[cOff + (long)m_loc * p.ldc + n_loc], av);
        }
      }
    }
  }
}

// ---------------- prep kernels ----------------
__global__ __launch_bounds__(256) void kConcatSplit(const float* __restrict__ h,
                                                    const float* __restrict__ hc,
                                                    unsigned short* __restrict__ Xh,
                                                    unsigned short* __restrict__ Xl) {
  long i = (((long)blockIdx.x) * 256 + threadIdx.x) * 4;
  long b = i >> 21;
  long rem = i & 2097151;
  const float* s = (rem < 1048576) ? (hc + b * 1048576 + rem) : (h + b * 1048576 + (rem - 1048576));
  f32x4 v = *(const f32x4*)s;
#pragma unroll
  for (int j = 0; j < 4; ++j) {
    float x = v[j];
    unsigned short hi = f2bf(x);
    Xh[i + j] = hi;
    Xl[i + j] = f2bf(x - bf2f(hi));
  }
}

__global__ __launch_bounds__(256) void kTransposeSplit(const float* __restrict__ src, long src_z,
                                                       int R, int C,
                                                       unsigned short* __restrict__ dh,
                                                       unsigned short* __restrict__ dl, long dst_z) {
  __shared__ float tile[32][33];
  const int z = blockIdx.z;
  const float* s = src + (long)z * src_z;
  const int c0 = blockIdx.x * 32, r0 = blockIdx.y * 32;
  const int tx = threadIdx.x & 31, ty = threadIdx.x >> 5;
  for (int i = 0; i < 32; i += 8)
    tile[ty + i][tx] = s[(long)(r0 + ty + i) * C + c0 + tx];
  __syncthreads();
  unsigned short* ph = dh + (long)z * dst_z;
  for (int i = 0; i < 32; i += 8) {
    int c = c0 + ty + i;
    float v = tile[tx][ty + i];
    unsigned short hv = f2bf(v);
    ph[(long)c * R + r0 + tx] = hv;
    if (dl) dl[(long)z * dst_z + (long)c * R + r0 + tx] = f2bf(v - bf2f(hv));
  }
}

// fp32 -> hi/lo bf16 planes
__global__ __launch_bounds__(256) void kSplitF(const float* __restrict__ src,
                                               unsigned short* __restrict__ hi,
                                               unsigned short* __restrict__ lo, int n4) {
  int i = blockIdx.x * 256 + threadIdx.x;
  if (i >= n4) return;
  f32x4 v = ((const f32x4*)src)[i];
#pragma unroll
  for (int j = 0; j < 4; ++j) {
    float x = v[j];
    unsigned short h = f2bf(x);
    hi[i * 4 + j] = h;
    lo[i * 4 + j] = f2bf(x - bf2f(h));
  }
}

// ---------------- softmax over banded score rows (1152 slots) ----------------
__global__ __launch_bounds__(256) void kSoftmax(const float* __restrict__ S,
                                                unsigned short* __restrict__ Ph,
                                                unsigned short* __restrict__ Pl) {
  __shared__ float red[4];
  const long r = blockIdx.x;
  const float* s = S + r * 1152;
  const int t = threadIdx.x;
  float v[5];
  float mx = -3e38f;
#pragma unroll
  for (int i = 0; i < 5; ++i) {
    int c = t + i * 256;
    v[i] = (c < 1152) ? s[c] : -3e38f;
    mx = fmaxf(mx, v[i]);
  }
  for (int o = 32; o; o >>= 1) mx = fmaxf(mx, __shfl_xor(mx, o));
  if ((t & 63) == 0) red[t >> 6] = mx;
  __syncthreads();
  mx = fmaxf(fmaxf(red[0], red[1]), fmaxf(red[2], red[3]));
  __syncthreads();
  float e[5]; float sum = 0.f;
#pragma unroll
  for (int i = 0; i < 5; ++i) {
    int c = t + i * 256;
    e[i] = (c < 1152) ? expf(v[i] - mx) : 0.f;
    sum += e[i];
  }
  for (int o = 32; o; o >>= 1) sum += __shfl_xor(sum, o);
  if ((t & 63) == 0) red[t >> 6] = sum;
  __syncthreads();
  sum = red[0] + red[1] + red[2] + red[3];
  const float inv = 1.0f / sum;
#pragma unroll
  for (int i = 0; i < 5; ++i) {
    int c = t + i * 256;
    if (c < 1152) {
      float pv = e[i] * inv;
      unsigned short hv = f2bf(pv);
      Ph[r * 1152 + c] = hv;
      Pl[r * 1152 + c] = f2bf(pv - bf2f(hv));
    }
  }
}

// ---------------- layernorms ----------------
DEV float blockReduceSum(float v, float* red) {
  for (int o = 32; o; o >>= 1) v += __shfl_xor(v, o);
  if ((threadIdx.x & 63) == 0) red[threadIdx.x >> 6] = v;
  __syncthreads();
  v = red[0] + red[1] + red[2] + red[3];
  __syncthreads();
  return v;
}

__global__ __launch_bounds__(256) void kLN1(const float* __restrict__ h, const float* __restrict__ aw,
                                            const float* __restrict__ g, const float* __restrict__ b,
                                            float* __restrict__ h1f, unsigned short* __restrict__ h1h) {
  __shared__ float red[4];
  const long r = blockIdx.x;
  const int t = threadIdx.x;
  float x[4]; float s = 0.f;
#pragma unroll
  for (int i = 0; i < 4; ++i) { int c = t + i * 256; x[i] = h[r * 1024 + c] + aw[r * 1024 + c]; s += x[i]; }
  float mu = blockReduceSum(s, red) * (1.0f / 1024.0f);
  float q = 0.f;
#pragma unroll
  for (int i = 0; i < 4; ++i) { float d = x[i] - mu; q += d * d; }
  float var = blockReduceSum(q, red) * (1.0f / 1024.0f);
  float rstd = 1.0f / sqrtf(var + 1e-5f);
#pragma unroll
  for (int i = 0; i < 4; ++i) {
    int c = t + i * 256;
    float y = (x[i] - mu) * rstd * g[c] + b[c];
    h1f[r * 1024 + c] = y;
    h1h[r * 1024 + c] = f2bf(y);
  }
}

__global__ __launch_bounds__(256) void kLN2(const float* __restrict__ h1f, const float* __restrict__ mom,
                                            const float* __restrict__ g, const float* __restrict__ b,
                                            float* __restrict__ out) {
  __shared__ float red[4];
  const long r = blockIdx.x;
  const int t = threadIdx.x;
  float x[4]; float s = 0.f;
#pragma unroll
  for (int i = 0; i < 4; ++i) { int c = t + i * 256; x[i] = h1f[r * 1024 + c] - mom[r * 1024 + c]; s += x[i]; }
  float mu = blockReduceSum(s, red) * (1.0f / 1024.0f);
  float q = 0.f;
#pragma unroll
  for (int i = 0; i < 4; ++i) { float d = x[i] - mu; q += d * d; }
  float var = blockReduceSum(q, red) * (1.0f / 1024.0f);
  float rstd = 1.0f / sqrtf(var + 1e-5f);
#pragma unroll
  for (int i = 0; i < 4; ++i) {
    int c = t + i * 256;
    out[r * 1024 + c] = (x[i] - mu) * rstd * g[c] + b[c];
  }
}

// ---------------- gate + bucketing ----------------
__global__ __launch_bounds__(256) void kGate(const float* __restrict__ h1f, const float* __restrict__ gw,
                                             const float* __restrict__ gb,
                                             int2* __restrict__ sel, float2* __restrict__ wgt) {
  const int w = threadIdx.x >> 6, lane = threadIdx.x & 63;
  const long r = (long)blockIdx.x * 4 + w;
  float acc[8] = {0, 0, 0, 0, 0, 0, 0, 0};
  const float* xr = h1f + r * 1024;
  for (int kk = lane; kk < 1024; kk += 64) {
    float x = xr[kk];
    const float* gg = gw + kk * 8;
#pragma unroll
    for (int e = 0; e < 8; ++e) acc[e] += x * gg[e];
  }
#pragma unroll
  for (int e = 0; e < 8; ++e)
    for (int o = 32; o; o >>= 1) acc[e] += __shfl_xor(acc[e], o);
  if (lane == 0) {
    float lg[8];
#pragma unroll
    for (int e = 0; e < 8; ++e) lg[e] = acc[e] + gb[e];
    int e0 = 0; float v0 = lg[0];
#pragma unroll
    for (int e = 1; e < 8; ++e) if (lg[e] > v0) { v0 = lg[e]; e0 = e; }
    int e1 = -1; float v1 = -3e38f;
#pragma unroll
    for (int e = 0; e < 8; ++e) if (e != e0 && lg[e] > v1) { v1 = lg[e]; e1 = e; }
    float ed = expf(v1 - v0);
    float si = 1.0f / (1.0f + ed);
    sel[r] = make_int2(e0, e1);
    wgt[r] = make_float2(si, ed * si);
  }
}

__global__ void kCount(const int2* __restrict__ sel, int* __restrict__ cnt) {
  int r = blockIdx.x * 256 + threadIdx.x;
  if (r < 4096) { int2 s = sel[r]; atomicAdd(&cnt[s.x], 1); atomicAdd(&cnt[s.y], 1); }
}
// 128-aligned per-expert offsets + compact tile map
__global__ void kScan(const int* __restrict__ cnt, int* __restrict__ off,
                      int2* __restrict__ tmap, int* __restrict__ tn) {
  if (threadIdx.x == 0) {
    int run = 0, nt = 0;
    for (int e = 0; e < 8; ++e) {
      off[e] = run;
      int nb = (cnt[e] + 127) >> 7;
      for (int j = 0; j < nb; ++j) { tmap[nt] = make_int2(e, run + (j << 7)); ++nt; }
      run += nb << 7;
    }
    *tn = nt;
  }
}
__global__ void kScatter(const int2* __restrict__ sel, const int* __restrict__ off,
                         int* __restrict__ cur, int* __restrict__ bucket, int2* __restrict__ slotof) {
  int r = blockIdx.x * 256 + threadIdx.x;
  if (r < 4096) {
    int2 s = sel[r];
    int a0 = off[s.x] + atomicAdd(&cur[s.x], 1);
    int a1 = off[s.y] + atomicAdd(&cur[s.y], 1);
    bucket[a0] = r; bucket[a1] = r;
    slotof[r] = make_int2(a0, a1);
  }
}

__global__ __launch_bounds__(256) void kCombine(const float* __restrict__ Z, const int2* __restrict__ slotof,
                                                const float2* __restrict__ wgt, const float* __restrict__ mom_in,
                                                float* __restrict__ mom_out) {
  const long r = blockIdx.x;
  const int t = threadIdx.x;
  int2 sl = slotof[r];
  float2 w = wgt[r];
  const float* z0 = Z + (long)sl.x * 1024;
  const float* z1 = Z + (long)sl.y * 1024;
#pragma unroll
  for (int i = 0; i < 4; ++i) {
    int c = t + i * 256;
    float moe = w.x * z0[c] + w.y * z1[c];
    mom_out[r * 1024 + c] = 0.7f * mom_in[r * 1024 + c] + moe;
  }
}

// ---------------------------------------------------------------------------
extern "C" void kernel_launch(void* const* d_in, const int* in_sizes, int n_in,
                              void* d_out, int out_size, void* d_ws, size_t ws_size,
                              hipStream_t stream) {
  (void)in_sizes; (void)n_in; (void)out_size; (void)ws_size;
  const float* h       = (const float*)d_in[0];
  const float* h_cache = (const float*)d_in[1];
  const float* pos     = (const float*)d_in[2];
  const float* mom_in  = (const float*)d_in[3];
  const float* Wq      = (const float*)d_in[4];
  const float* Wk      = (const float*)d_in[5];
  const float* Wv      = (const float*)d_in[6];
  const float* Wo      = (const float*)d_in[7];
  const float* gate_w  = (const float*)d_in[8];
  const float* gate_b  = (const float*)d_in[9];
  const float* w1      = (const float*)d_in[10];
  const float* b1      = (const float*)d_in[11];
  const float* w2      = (const float*)d_in[12];
  const float* b2      = (const float*)d_in[13];
  const float* ln1g    = (const float*)d_in[14];
  const float* ln1b    = (const float*)d_in[15];
  const float* ln2g    = (const float*)d_in[16];
  const float* ln2b    = (const float*)d_in[17];
  float* out = (float*)d_out;

  char* ws = (char*)d_ws;
  // Phase-aliased region map (total ~391 MB). Lifetimes commented.
  float*          S     = (float*)(ws + 0L);               // ph2 per half
  unsigned short* Y1    = (unsigned short*)(ws + 0L);      // ph5 (9216x4096)
  unsigned short* Oh    = (unsigned short*)(ws + 0L);      // ph3
  unsigned short* Ol    = (unsigned short*)(ws + 8388608L);
  float*          Ppos  = (float*)(ws + 75497472L);        // ph2
  unsigned short* w1T   = (unsigned short*)(ws + 75497472L);   // ph5
  unsigned short* Ph    = (unsigned short*)(ws + 142606336L);  // ph2
  unsigned short* Pl    = (unsigned short*)(ws + 180355072L);
  unsigned short* w2T   = (unsigned short*)(ws + 142606336L);  // ph5
  unsigned short* Xh    = (unsigned short*)(ws + 218103808L);  // ph0-1
  unsigned short* Xl    = (unsigned short*)(ws + 234881024L);
  float*          attnO = (float*)(ws + 218103808L);       // ph2-3 (alias Xh)
  float*          attnWo= (float*)(ws + 234881024L);       // ph3 (alias Xl)
  unsigned short* kh    = (unsigned short*)(ws + 251658240L);  // ph1-2
  unsigned short* kl    = (unsigned short*)(ws + 268435456L);
  float*          h1f   = (float*)(ws + 251658240L);       // ph3+ (alias kh)
  unsigned short* h1h   = (unsigned short*)(ws + 268435456L);  // ph3+ (alias kl)
  unsigned short* VTh   = (unsigned short*)(ws + 285212672L);  // ph1-2
  unsigned short* VTl   = (unsigned short*)(ws + 301989888L);
  unsigned short* qh    = (unsigned short*)(ws + 318767104L);  // ph1-2
  unsigned short* ql    = (unsigned short*)(ws + 327155712L);
  float*          qtmp  = (float*)(ws + 335544320L);       // ph1
  float*          Z     = (float*)(ws + 335544320L);       // ph5-6 (9216x1024)
  unsigned short* WqTh  = (unsigned short*)(ws + 373293056L);
  unsigned short* WqTl  = (unsigned short*)(ws + 375390208L);
  unsigned short* WkTh  = (unsigned short*)(ws + 377487360L);
  unsigned short* WkTl  = (unsigned short*)(ws + 379584512L);
  unsigned short* WvTh  = (unsigned short*)(ws + 381681664L);
  unsigned short* WvTl  = (unsigned short*)(ws + 383778816L);
  unsigned short* WoTh  = (unsigned short*)(ws + 385875968L);
  unsigned short* WoTl  = (unsigned short*)(ws + 387973120L);
  unsigned short* posTh = (unsigned short*)(ws + 390070272L);
  unsigned short* posTl = (unsigned short*)(ws + 390332416L);
  int2*           sel   = (int2*)(ws + 390594560L);
  float2*         wgt   = (float2*)(ws + 390627328L);
  int2*           slotof= (int2*)(ws + 390660096L);
  int*            bucket= (int*)(ws + 390692864L);         // 9216 ints
  int*            cnt   = (int*)(ws + 390729728L);
  int*            cur   = (int*)(ws + 390729760L);
  int*            off   = (int*)(ws + 390729792L);
  int2*           tmap  = (int2*)(ws + 390729856L);        // 80 tiles
  int*            tn    = (int*)(ws + 390730496L);

  // ---- phase 0: concat+split X, transpose+split weights / pos ----
  kConcatSplit<<<8192, 256, 0, stream>>>(h, h_cache, Xh, Xl);
  kTransposeSplit<<<dim3(32, 32, 1), 256, 0, stream>>>(Wq, 0, 1024, 1024, WqTh, WqTl, 0);
  kTransposeSplit<<<dim3(32, 32, 1), 256, 0, stream>>>(Wk, 0, 1024, 1024, WkTh, WkTl, 0);
  kTransposeSplit<<<dim3(32, 32, 1), 256, 0, stream>>>(Wv, 0, 1024, 1024, WvTh, WvTl, 0);
  kTransposeSplit<<<dim3(32, 32, 1), 256, 0, stream>>>(Wo, 0, 1024, 1024, WoTh, WoTl, 0);
  kTransposeSplit<<<dim3(32, 4, 1), 256, 0, stream>>>(pos, 0, 128, 1024, posTh, posTl, 0);

  // ---- phase 1: projections ----
  hipMemsetAsync(qtmp, 0, 16777216L, stream);
  {  // qtmp = h @ Wq (fp32 atomic, K-split 2)
    GemmP p{}; p.zdiv = 1; p.split = 1; p.mode = 5;
    p.Ah = Xh + 1048576; p.Al = Xl + 1048576; p.Bh = WqTh; p.Bl = WqTl;
    p.C = qtmp;
    p.lda = 1024; p.ldb = 1024; p.ldc = 1024; p.K = 1024; p.Kc = 512; p.nx = 8;
    p.a_zo = 2097152; p.c_zo = 1048576; p.c_y = 131072; p.c_x = 128;
    kGemm<1><<<dim3(16, 8, 4), 256, 0, stream>>>(p);
  }
  kSplitF<<<4096, 256, 0, stream>>>(qtmp, qh, ql, 1048576);
  {  // k = X @ Wk (split store)
    GemmP p{}; p.zdiv = 1; p.split = 1; p.mode = 1;
    p.Ah = Xh; p.Al = Xl; p.Bh = WkTh; p.Bl = WkTl;
    p.C = kh; p.C2 = kl;
    p.lda = 1024; p.ldb = 1024; p.ldc = 1024; p.K = 1024; p.Kc = 1024; p.nx = 8;
    p.c_y = 131072; p.c_x = 128;
    kGemm<1><<<dim3(8, 64, 1), 256, 0, stream>>>(p);
  }
  {  // VT = (X @ Wv)^T per batch: [b][hd*128+d][key]
    GemmP p{}; p.zdiv = 1; p.split = 1; p.mode = 2;
    p.Ah = Xh; p.Al = Xl; p.Bh = WvTh; p.Bl = WvTl;
    p.C = VTh; p.C2 = VTl;
    p.lda = 1024; p.ldb = 1024; p.ldc = 2048; p.K = 1024; p.Kc = 1024; p.nx = 8;
    p.a_zo = 2097152; p.c_zo = 2097152; p.c_y = 128; p.c_x = 262144;
    kGemm<1><<<dim3(8, 16, 4), 256, 0, stream>>>(p);
  }

  // ---- phase 2: attention, per batch-half (z = 16 heads) ----
  hipMemsetAsync(attnO, 0, 16777216L, stream);
  for (int hf = 0; hf < 2; ++hf) {
    const long qo = hf * 2097152L, ko = hf * 4194304L, vo = hf * 4194304L;
    {  // Ppos[z][m][l] = q . posT[l]
      GemmP p{}; p.zdiv = 8; p.split = 1; p.mode = 0;
      p.Ah = qh + qo; p.Al = ql + qo; p.Bh = posTh; p.Bl = posTl;
      p.C = Ppos;
      p.lda = 1024; p.ldb = 128; p.ldc = 1024; p.K = 128; p.Kc = 128; p.nx = 8;
      p.a_zo = 1048576; p.a_zi = 128;
      p.c_zo = 8388608; p.c_zi = 1048576; p.c_y = 131072; p.c_x = 128;
      kGemm<1><<<dim3(8, 8, 16), 256, 0, stream>>>(p);
    }
    {  // banded scores with fused skew lookup + mask + 1/32
      GemmP p{}; p.zdiv = 8; p.split = 1; p.mode = 3;
      p.Ah = qh + qo; p.Al = ql + qo; p.Bh = kh + ko; p.Bl = kl + ko;
      p.C = S; p.xtra = Ppos;
      p.lda = 1024; p.ldb = 1024; p.ldc = 1152; p.xld = 1024; p.K = 128; p.Kc = 128; p.nx = 9;
      p.a_zo = 1048576; p.a_zi = 128;
      p.b_zo = 2097152; p.b_zi = 128; p.b_y = 131072;
      p.c_zo = 9437184; p.c_zi = 1179648; p.c_y = 147456; p.c_x = 128;
      p.x_zo = 8388608; p.x_zi = 1048576; p.x_y = 131072;
      kGemm<1><<<dim3(9, 8, 16), 256, 0, stream>>>(p);
    }
    kSoftmax<<<16384, 256, 0, stream>>>(S, Ph, Pl);
    {  // attnO += P @ V (K-split 3, fp32 atomic)
      GemmP p{}; p.zdiv = 8; p.split = 1; p.mode = 5;
      p.Ah = Ph; p.Al = Pl; p.Bh = VTh + vo; p.Bl = VTl + vo;
      p.C = attnO + hf * 2097152L;
      p.lda = 1152; p.ldb = 2048; p.ldc = 1024; p.K = 1152; p.Kc = 384; p.nx = 1;
      p.a_zo = 9437184; p.a_zi = 1179648;
      p.b_zo = 2097152; p.b_zi = 262144; p.b_y = 128;
      p.c_zo = 1048576; p.c_zi = 128; p.c_y = 131072; p.c_x = 128;
      kGemm<1><<<dim3(3, 8, 16), 256, 0, stream>>>(p);
    }
  }

  // ---- phase 3: O split + Wo projection (K-split 2) + LN1 ----
  kSplitF<<<4096, 256, 0, stream>>>(attnO, Oh, Ol, 1048576);
  hipMemsetAsync(attnWo, 0, 16777216L, stream);
  {
    GemmP p{}; p.zdiv = 1; p.split = 1; p.mode = 5;
    p.Ah = Oh; p.Al = Ol; p.Bh = WoTh; p.Bl = WoTl;
    p.C = attnWo;
    p.lda = 1024; p.ldb = 1024; p.ldc = 1024; p.K = 1024; p.Kc = 512; p.nx = 8;
    p.c_y = 131072; p.c_x = 128;
    kGemm<1><<<dim3(16, 32, 1), 256, 0, stream>>>(p);
  }
  kLN1<<<4096, 256, 0, stream>>>(h, attnWo, ln1g, ln1b, h1f, h1h);

  // ---- phase 4: gate + compact buckets ----
  kGate<<<1024, 256, 0, stream>>>(h1f, gate_w, gate_b, sel, wgt);
  hipMemsetAsync(cnt, 0, 64, stream);              // cnt + cur
  hipMemsetAsync(bucket, 0, 36864, stream);        // pad slots -> row 0
  kCount<<<16, 256, 0, stream>>>(sel, cnt);
  kScan<<<1, 64, 0, stream>>>(cnt, off, tmap, tn);
  kScatter<<<16, 256, 0, stream>>>(sel, off, cur, bucket, slotof);

  // ---- phase 5: MoE (single bf16, compact tile map, counted-vmcnt dbuf) ----
  kTransposeSplit<<<dim3(128, 32, 8), 256, 0, stream>>>(w1, 4194304L, 1024, 4096, w1T, nullptr, 4194304L);
  kTransposeSplit<<<dim3(32, 128, 8), 256, 0, stream>>>(w2, 4194304L, 4096, 1024, w2T, nullptr, 4194304L);
  {  // Y1 = relu(gather(h1) @ w1[e] + b1[e])
    GemmP p{}; p.zdiv = 1; p.split = 0; p.mode = 4;
    p.Ah = h1h; p.Bh = w1T;
    p.C = Y1;
    p.idx = bucket; p.tmap = tmap; p.tn = tn;
    p.bias = b1; p.bias_z = 4096;
    p.lda = 1024; p.ldb = 1024; p.ldc = 4096; p.K = 1024; p.Kc = 1024; p.nx = 32;
    p.b_zi = 4194304; p.c_x = 128;
    kGemm<0><<<dim3(32, 72, 1), 256, 0, stream>>>(p);
  }
  hipMemsetAsync(Z, 0, 37748736L, stream);
  {  // Z += Y1 @ w2[e] + b2[e]  (K-split 2, fp32 atomic)
    GemmP p{}; p.zdiv = 1; p.split = 0; p.mode = 5;
    p.Ah = Y1; p.Bh = w2T;
    p.C = Z;
    p.tmap = tmap; p.tn = tn;
    p.bias = b2; p.bias_z = 1024;
    p.lda = 4096; p.ldb = 4096; p.ldc = 1024; p.K = 4096; p.Kc = 2048; p.nx = 8;
    p.b_zi = 4194304; p.c_x = 128;
    kGemm<0><<<dim3(16, 72, 1), 256, 0, stream>>>(p);
  }

  // ---- phase 6: combine + momentum + LN2 ----
  float* mom_out = out + 4194304;
  kCombine<<<4096, 256, 0, stream>>>(Z, slotof, wgt, mom_in, mom_out);
  kLN2<<<4096, 256, 0, stream>>>(h1f, mom_out, ln2g, ln2b, out);
}

// Round 6
// 1466.547 us; speedup vs baseline: 1.1254x; 1.0243x over previous
//
#include <hip/hip_runtime.h>

// ---------------------------------------------------------------------------
// TransformerSeqLayer on MI355X.
// Banded (window 1024) rel-pos attention + LN + top-2 MoE + momentum + LN.
// This round: MoE GEMMs (Y1, Z) move to kGemmW — 128x256 output tile,
// 512 threads / 8 waves, dbuf counted-vmcnt. Theory: 128^2 tile was at its
// staging-BW roofline (64 FLOP/B * 6.7 TB/s delivered = 430 TF ~= measured
// 400 TF); BN=256 raises AI to 87 FLOP/B and cuts staged bytes 1.36x.
// split=1 GEMMs unchanged (in-run control). XOR swizzle retained (conflicts=0).
// ---------------------------------------------------------------------------

typedef short short8 __attribute__((ext_vector_type(8)));
typedef float f32x4 __attribute__((ext_vector_type(4)));

typedef const void __attribute__((address_space(1)))* gas1_t;
typedef void __attribute__((address_space(3)))* las3_t;
#define ASYNC16(G, L) __builtin_amdgcn_global_load_lds((gas1_t)(G), (las3_t)(L), 16, 0, 0)

#define DEV __device__ __forceinline__

DEV float bf2f(unsigned short u) {
  union { unsigned int u; float f; } x; x.u = ((unsigned int)u) << 16; return x.f;
}
DEV unsigned short f2bf(float f) {
  union { float f; unsigned int u; } x; x.f = f;
  unsigned int r = x.u + 0x7fffu + ((x.u >> 16) & 1u);
  return (unsigned short)(r >> 16);
}

// ---------------------------------------------------------------------------
// Generic 128x128 MFMA GEMM (split bf16 path). C[m,n] = sum_k A[m,k]*BT[n,k].
// Modes: 0 fp32+bias store, 1 split-bf16 store, 2 split-bf16 transposed store,
//        3 score epilogue (+Ppos skew lookup, mask, /32), 5 atomicAdd fp32.
// LDS [128][32]-short tiles, chunk-XOR swizzle: LDS[r][c8] holds global chunk
// c8 ^ ((r>>1)&3); staging source pre-swizzled, reads apply same XOR ->
// conflict-free ds_read_b128 (verified SQ_LDS_BANK_CONFLICT=0).
// ---------------------------------------------------------------------------
struct GemmP {
  const unsigned short* Ah; const unsigned short* Al;
  const unsigned short* Bh; const unsigned short* Bl;
  void* C; void* C2;
  const float* bias;
  const float* xtra;
  const int* idx; const int2* tmap; const int* tn;
  long a_zo, a_zi;
  long b_zo, b_zi, b_y;
  long c_zo, c_zi, c_y, c_x;
  long x_zo, x_zi, x_y;
  long bias_z;
  int lda, ldb, ldc, xld;
  int K, Kc, nx, zdiv, mode, split;
};

template <int SPLIT>
__global__ __launch_bounds__(256) void kGemm(GemmP p) {
  const int t = threadIdx.x;
  const int bx = blockIdx.x, by = blockIdx.y, bz = blockIdx.z;
  const int zo = bz / p.zdiv, zi = bz % p.zdiv;
  const int bxn = bx % p.nx, kc = bx / p.nx;

  long aOff = 0, bOff, cOff;
  long ar0, ar1;
  int e = zi;
  if (p.tmap) {
    if (by >= *p.tn) return;
    int2 tm = p.tmap[by];
    e = tm.x;
    long base = tm.y;
    cOff = base * p.ldc + (long)bxn * p.c_x;
    bOff = (long)e * p.b_zi + (long)bxn * 128L * p.ldb;
    if (p.idx) { ar0 = p.idx[base + (t >> 2)]; ar1 = p.idx[base + 64 + (t >> 2)]; }
    else { ar0 = base + (t >> 2); ar1 = ar0 + 64; }
  } else {
    aOff = (long)zo * p.a_zo + (long)zi * p.a_zi;
    bOff = (long)zo * p.b_zo + (long)zi * p.b_zi + (long)by * p.b_y + (long)bxn * 128L * p.ldb;
    cOff = (long)zo * p.c_zo + (long)zi * p.c_zi + (long)by * p.c_y + (long)bxn * p.c_x;
    ar0 = by * 128 + (t >> 2); ar1 = ar0 + 64;
  }

  // staging col, XOR-swizzled: chunk (t&3) ^ ((row>>1)&3) with row = t>>2
  const int scol = (((t & 3) ^ ((t >> 3) & 3)) << 3);
  const unsigned short* A0h = p.Ah + aOff + ar0 * (long)p.lda + scol;
  const unsigned short* A1h = p.Ah + aOff + ar1 * (long)p.lda + scol;
  const unsigned short* B0h = p.Bh + bOff + (long)(t >> 2) * p.ldb + scol;
  const unsigned short* B1h = B0h + 64L * p.ldb;
  const unsigned short *A0l = nullptr, *A1l = nullptr, *B0l = nullptr, *B1l = nullptr;
  if (SPLIT) {
    A0l = p.Al + aOff + ar0 * (long)p.lda + scol;
    A1l = p.Al + aOff + ar1 * (long)p.lda + scol;
    B0l = p.Bl + bOff + (long)(t >> 2) * p.ldb + scol;
    B1l = B0l + 64L * p.ldb;
  }

  const int wave = t >> 6;
  const int lane = t & 63;
  const int quad = lane >> 4, l15 = lane & 15;
  const int wr = (wave >> 1) * 64, wc = (wave & 1) * 64;
  // fragment-read chunk, same XOR: quad ^ ((row>>1)&3), row = ...16*i + l15
  const int qs = ((quad ^ ((l15 >> 1) & 3)) << 3);

  f32x4 acc[4][4] = {};
  const int kt0 = (kc * p.Kc) >> 5;
  const int ktN = kt0 + (p.Kc >> 5);

  __shared__ short sAh[4096], sAl[4096], sBh[4096], sBl[4096];
  for (int kt = kt0; kt < ktN; ++kt) {
    const int k0 = kt << 5;
    ASYNC16(A0h + k0, &sAh[wave * 512]);
    ASYNC16(A1h + k0, &sAh[2048 + wave * 512]);
    ASYNC16(B0h + k0, &sBh[wave * 512]);
    ASYNC16(B1h + k0, &sBh[2048 + wave * 512]);
    if (SPLIT) {
      ASYNC16(A0l + k0, &sAl[wave * 512]);
      ASYNC16(A1l + k0, &sAl[2048 + wave * 512]);
      ASYNC16(B0l + k0, &sBl[wave * 512]);
      ASYNC16(B1l + k0, &sBl[2048 + wave * 512]);
    }
    __syncthreads();
    short8 fa[4], fb[4];
#pragma unroll
    for (int i = 0; i < 4; ++i) {
      fa[i] = *(const short8*)&sAh[(wr + i * 16 + l15) * 32 + qs];
      fb[i] = *(const short8*)&sBh[(wc + i * 16 + l15) * 32 + qs];
    }
#pragma unroll
    for (int bi = 0; bi < 4; ++bi)
#pragma unroll
      for (int bj = 0; bj < 4; ++bj)
        acc[bi][bj] = __builtin_amdgcn_mfma_f32_16x16x32_bf16(fa[bi], fb[bj], acc[bi][bj], 0, 0, 0);
    if (SPLIT) {
      short8 ga[4], gb[4];
#pragma unroll
      for (int i = 0; i < 4; ++i) {
        ga[i] = *(const short8*)&sAl[(wr + i * 16 + l15) * 32 + qs];
        gb[i] = *(const short8*)&sBl[(wc + i * 16 + l15) * 32 + qs];
      }
#pragma unroll
      for (int bi = 0; bi < 4; ++bi)
#pragma unroll
        for (int bj = 0; bj < 4; ++bj) {
          acc[bi][bj] = __builtin_amdgcn_mfma_f32_16x16x32_bf16(fa[bi], gb[bj], acc[bi][bj], 0, 0, 0);
          acc[bi][bj] = __builtin_amdgcn_mfma_f32_16x16x32_bf16(ga[bi], fb[bj], acc[bi][bj], 0, 0, 0);
        }
    }
    __syncthreads();
  }

  long xOff = 0;
  if (p.mode == 3) xOff = (long)zo * p.x_zo + (long)zi * p.x_zi + (long)by * p.x_y;
#pragma unroll
  for (int bj = 0; bj < 4; ++bj) {
    const int n_loc = wc + bj * 16 + l15;
    float bv = 0.0f;
    if (p.bias) bv = p.bias[(long)e * p.bias_z + (long)bxn * 128 + n_loc];
#pragma unroll
    for (int bi = 0; bi < 4; ++bi) {
#pragma unroll
      for (int r = 0; r < 4; ++r) {
        const int m_loc = wr + bi * 16 + quad * 4 + r;   // C/D: row=quad*4+reg, col=lane&15
        float v = acc[bi][bj][r];
        if (p.mode == 0) {
          ((float*)p.C)[cOff + (long)m_loc * p.ldc + n_loc] = v + bv;
        } else if (p.mode == 1) {
          long a = cOff + (long)m_loc * p.ldc + n_loc;
          unsigned short hv = f2bf(v);
          ((unsigned short*)p.C)[a] = hv;
          ((unsigned short*)p.C2)[a] = f2bf(v - bf2f(hv));
        } else if (p.mode == 2) {
          long a = cOff + (long)n_loc * p.ldc + m_loc;
          unsigned short hv = f2bf(v);
          ((unsigned short*)p.C)[a] = hv;
          ((unsigned short*)p.C2)[a] = f2bf(v - bf2f(hv));
        } else if (p.mode == 3) {
          int l = bxn * 128 + n_loc - m_loc;
          float outv;
          if ((unsigned)l < 1024u)
            outv = (v + p.xtra[xOff + (long)m_loc * p.xld + l]) * 0.03125f;
          else
            outv = -1e30f;
          ((float*)p.C)[cOff + (long)m_loc * p.ldc + n_loc] = outv;
        } else if (p.mode == 4) {
          float rv = v + bv;
          rv = rv > 0.0f ? rv : 0.0f;
          ((unsigned short*)p.C)[cOff + (long)m_loc * p.ldc + n_loc] = f2bf(rv);
        } else {  // mode 5: atomic fp32 accumulate, bias only in chunk 0
          float av = v + (kc == 0 ? bv : 0.0f);
          atomicAdd(&((float*)p.C)[cOff + (long)m_loc * p.ldc + n_loc], av);
        }
      }
    }
  }
}

// ---------------------------------------------------------------------------
// Wide MoE GEMM: 128x256 tile, 512 threads / 8 waves (2M x 4N), single bf16.
// tmap mode only. AI = 87 FLOP/B (vs 64 at 128x128) -> higher staging-BW
// roofline. LDS: A[2][128][32] + B[2][256][32] shorts = 48 KB (3 blocks/CU).
// Per K-step per thread: 3 ASYNC16 (A row t>>2; B rows t>>2 and 128+t>>2).
// Same chunk-XOR swizzle; (r+128)>>1 == r>>1 (mod 4) so one scol serves all.
// Modes: 4 bias+relu+bf16 store, 5 atomicAdd fp32 (+bias when kc==0).
// ---------------------------------------------------------------------------
__global__ __launch_bounds__(512) void kGemmW(GemmP p) {
  const int t = threadIdx.x;
  const int bx = blockIdx.x, by = blockIdx.y;
  const int bxn = bx % p.nx, kc = bx / p.nx;
  if (by >= *p.tn) return;
  int2 tm = p.tmap[by];
  const int e = tm.x;
  const long base = tm.y;
  const long cOff = base * p.ldc + (long)bxn * p.c_x;          // c_x = 256
  const long bOff = (long)e * p.b_zi + (long)bxn * 256L * p.ldb;
  long ar0;
  if (p.idx) ar0 = p.idx[base + (t >> 2)];
  else       ar0 = base + (t >> 2);

  const int scol = (((t & 3) ^ ((t >> 3) & 3)) << 3);
  const unsigned short* A0 = p.Ah + ar0 * (long)p.lda + scol;
  const unsigned short* B0 = p.Bh + bOff + (long)(t >> 2) * p.ldb + scol;
  const unsigned short* B1 = B0 + 128L * p.ldb;

  __shared__ short sA[2][4096], sB[2][8192];
  const int wave = t >> 6;
  const int lane = t & 63;
  const int quad = lane >> 4, l15 = lane & 15;
  const int wr = (wave >> 2) * 64;        // 2 wave-rows  (M=128)
  const int wc = (wave & 3) * 64;         // 4 wave-cols  (N=256)
  const int qs = ((quad ^ ((l15 >> 1) & 3)) << 3);

  f32x4 acc[4][4] = {};
  const int kt0 = (kc * p.Kc) >> 5;
  const int ktN = kt0 + (p.Kc >> 5);
  int cur = 0;
  {
    const int k0 = kt0 << 5;
    ASYNC16(A0 + k0, &sA[0][wave * 512]);
    ASYNC16(B0 + k0, &sB[0][wave * 512]);
    ASYNC16(B1 + k0, &sB[0][4096 + wave * 512]);
  }
  for (int kt = kt0; kt < ktN; ++kt) {
    if (kt + 1 < ktN) {
      const int k1 = (kt + 1) << 5;
      ASYNC16(A0 + k1, &sA[cur ^ 1][wave * 512]);
      ASYNC16(B0 + k1, &sB[cur ^ 1][wave * 512]);
      ASYNC16(B1 + k1, &sB[cur ^ 1][4096 + wave * 512]);
      asm volatile("s_waitcnt vmcnt(3)" ::: "memory");
    } else {
      asm volatile("s_waitcnt vmcnt(0)" ::: "memory");
    }
    __builtin_amdgcn_s_barrier();
    short8 fa[4], fb[4];
#pragma unroll
    for (int i = 0; i < 4; ++i) {
      fa[i] = *(const short8*)&sA[cur][(wr + i * 16 + l15) * 32 + qs];
      fb[i] = *(const short8*)&sB[cur][(wc + i * 16 + l15) * 32 + qs];
    }
#pragma unroll
    for (int bi = 0; bi < 4; ++bi)
#pragma unroll
      for (int bj = 0; bj < 4; ++bj)
        acc[bi][bj] = __builtin_amdgcn_mfma_f32_16x16x32_bf16(fa[bi], fb[bj], acc[bi][bj], 0, 0, 0);
    __builtin_amdgcn_s_barrier();
    cur ^= 1;
  }

#pragma unroll
  for (int bj = 0; bj < 4; ++bj) {
    const int n_loc = wc + bj * 16 + l15;
    float bv = 0.0f;
    if (p.bias) bv = p.bias[(long)e * p.bias_z + (long)bxn * 256 + n_loc];
#pragma unroll
    for (int bi = 0; bi < 4; ++bi) {
#pragma unroll
      for (int r = 0; r < 4; ++r) {
        const int m_loc = wr + bi * 16 + quad * 4 + r;
        float v = acc[bi][bj][r];
        if (p.mode == 4) {
          float rv = v + bv;
          rv = rv > 0.0f ? rv : 0.0f;
          ((unsigned short*)p.C)[cOff + (long)m_loc * p.ldc + n_loc] = f2bf(rv);
        } else {  // mode 5
          float av = v + (kc == 0 ? bv : 0.0f);
          atomicAdd(&((float*)p.C)[cOff + (long)m_loc * p.ldc + n_loc], av);
        }
      }
    }
  }
}

// ---------------- prep kernels ----------------
__global__ __launch_bounds__(256) void kConcatSplit(const float* __restrict__ h,
                                                    const float* __restrict__ hc,
                                                    unsigned short* __restrict__ Xh,
                                                    unsigned short* __restrict__ Xl) {
  long i = (((long)blockIdx.x) * 256 + threadIdx.x) * 4;
  long b = i >> 21;
  long rem = i & 2097151;
  const float* s = (rem < 1048576) ? (hc + b * 1048576 + rem) : (h + b * 1048576 + (rem - 1048576));
  f32x4 v = *(const f32x4*)s;
#pragma unroll
  for (int j = 0; j < 4; ++j) {
    float x = v[j];
    unsigned short hi = f2bf(x);
    Xh[i + j] = hi;
    Xl[i + j] = f2bf(x - bf2f(hi));
  }
}

__global__ __launch_bounds__(256) void kTransposeSplit(const float* __restrict__ src, long src_z,
                                                       int R, int C,
                                                       unsigned short* __restrict__ dh,
                                                       unsigned short* __restrict__ dl, long dst_z) {
  __shared__ float tile[32][33];
  const int z = blockIdx.z;
  const float* s = src + (long)z * src_z;
  const int c0 = blockIdx.x * 32, r0 = blockIdx.y * 32;
  const int tx = threadIdx.x & 31, ty = threadIdx.x >> 5;
  for (int i = 0; i < 32; i += 8)
    tile[ty + i][tx] = s[(long)(r0 + ty + i) * C + c0 + tx];
  __syncthreads();
  unsigned short* ph = dh + (long)z * dst_z;
  for (int i = 0; i < 32; i += 8) {
    int c = c0 + ty + i;
    float v = tile[tx][ty + i];
    unsigned short hv = f2bf(v);
    ph[(long)c * R + r0 + tx] = hv;
    if (dl) dl[(long)z * dst_z + (long)c * R + r0 + tx] = f2bf(v - bf2f(hv));
  }
}

// fp32 -> hi/lo bf16 planes
__global__ __launch_bounds__(256) void kSplitF(const float* __restrict__ src,
                                               unsigned short* __restrict__ hi,
                                               unsigned short* __restrict__ lo, int n4) {
  int i = blockIdx.x * 256 + threadIdx.x;
  if (i >= n4) return;
  f32x4 v = ((const f32x4*)src)[i];
#pragma unroll
  for (int j = 0; j < 4; ++j) {
    float x = v[j];
    unsigned short h = f2bf(x);
    hi[i * 4 + j] = h;
    lo[i * 4 + j] = f2bf(x - bf2f(h));
  }
}

// ---------------- softmax over banded score rows (1152 slots) ----------------
__global__ __launch_bounds__(256) void kSoftmax(const float* __restrict__ S,
                                                unsigned short* __restrict__ Ph,
                                                unsigned short* __restrict__ Pl) {
  __shared__ float red[4];
  const long r = blockIdx.x;
  const float* s = S + r * 1152;
  const int t = threadIdx.x;
  float v[5];
  float mx = -3e38f;
#pragma unroll
  for (int i = 0; i < 5; ++i) {
    int c = t + i * 256;
    v[i] = (c < 1152) ? s[c] : -3e38f;
    mx = fmaxf(mx, v[i]);
  }
  for (int o = 32; o; o >>= 1) mx = fmaxf(mx, __shfl_xor(mx, o));
  if ((t & 63) == 0) red[t >> 6] = mx;
  __syncthreads();
  mx = fmaxf(fmaxf(red[0], red[1]), fmaxf(red[2], red[3]));
  __syncthreads();
  float e[5]; float sum = 0.f;
#pragma unroll
  for (int i = 0; i < 5; ++i) {
    int c = t + i * 256;
    e[i] = (c < 1152) ? expf(v[i] - mx) : 0.f;
    sum += e[i];
  }
  for (int o = 32; o; o >>= 1) sum += __shfl_xor(sum, o);
  if ((t & 63) == 0) red[t >> 6] = sum;
  __syncthreads();
  sum = red[0] + red[1] + red[2] + red[3];
  const float inv = 1.0f / sum;
#pragma unroll
  for (int i = 0; i < 5; ++i) {
    int c = t + i * 256;
    if (c < 1152) {
      float pv = e[i] * inv;
      unsigned short hv = f2bf(pv);
      Ph[r * 1152 + c] = hv;
      Pl[r * 1152 + c] = f2bf(pv - bf2f(hv));
    }
  }
}

// ---------------- layernorms ----------------
DEV float blockReduceSum(float v, float* red) {
  for (int o = 32; o; o >>= 1) v += __shfl_xor(v, o);
  if ((threadIdx.x & 63) == 0) red[threadIdx.x >> 6] = v;
  __syncthreads();
  v = red[0] + red[1] + red[2] + red[3];
  __syncthreads();
  return v;
}

__global__ __launch_bounds__(256) void kLN1(const float* __restrict__ h, const float* __restrict__ aw,
                                            const float* __restrict__ g, const float* __restrict__ b,
                                            float* __restrict__ h1f, unsigned short* __restrict__ h1h) {
  __shared__ float red[4];
  const long r = blockIdx.x;
  const int t = threadIdx.x;
  float x[4]; float s = 0.f;
#pragma unroll
  for (int i = 0; i < 4; ++i) { int c = t + i * 256; x[i] = h[r * 1024 + c] + aw[r * 1024 + c]; s += x[i]; }
  float mu = blockReduceSum(s, red) * (1.0f / 1024.0f);
  float q = 0.f;
#pragma unroll
  for (int i = 0; i < 4; ++i) { float d = x[i] - mu; q += d * d; }
  float var = blockReduceSum(q, red) * (1.0f / 1024.0f);
  float rstd = 1.0f / sqrtf(var + 1e-5f);
#pragma unroll
  for (int i = 0; i < 4; ++i) {
    int c = t + i * 256;
    float y = (x[i] - mu) * rstd * g[c] + b[c];
    h1f[r * 1024 + c] = y;
    h1h[r * 1024 + c] = f2bf(y);
  }
}

__global__ __launch_bounds__(256) void kLN2(const float* __restrict__ h1f, const float* __restrict__ mom,
                                            const float* __restrict__ g, const float* __restrict__ b,
                                            float* __restrict__ out) {
  __shared__ float red[4];
  const long r = blockIdx.x;
  const int t = threadIdx.x;
  float x[4]; float s = 0.f;
#pragma unroll
  for (int i = 0; i < 4; ++i) { int c = t + i * 256; x[i] = h1f[r * 1024 + c] - mom[r * 1024 + c]; s += x[i]; }
  float mu = blockReduceSum(s, red) * (1.0f / 1024.0f);
  float q = 0.f;
#pragma unroll
  for (int i = 0; i < 4; ++i) { float d = x[i] - mu; q += d * d; }
  float var = blockReduceSum(q, red) * (1.0f / 1024.0f);
  float rstd = 1.0f / sqrtf(var + 1e-5f);
#pragma unroll
  for (int i = 0; i < 4; ++i) {
    int c = t + i * 256;
    out[r * 1024 + c] = (x[i] - mu) * rstd * g[c] + b[c];
  }
}

// ---------------- gate + bucketing ----------------
__global__ __launch_bounds__(256) void kGate(const float* __restrict__ h1f, const float* __restrict__ gw,
                                             const float* __restrict__ gb,
                                             int2* __restrict__ sel, float2* __restrict__ wgt) {
  const int w = threadIdx.x >> 6, lane = threadIdx.x & 63;
  const long r = (long)blockIdx.x * 4 + w;
  float acc[8] = {0, 0, 0, 0, 0, 0, 0, 0};
  const float* xr = h1f + r * 1024;
  for (int kk = lane; kk < 1024; kk += 64) {
    float x = xr[kk];
    const float* gg = gw + kk * 8;
#pragma unroll
    for (int e = 0; e < 8; ++e) acc[e] += x * gg[e];
  }
#pragma unroll
  for (int e = 0; e < 8; ++e)
    for (int o = 32; o; o >>= 1) acc[e] += __shfl_xor(acc[e], o);
  if (lane == 0) {
    float lg[8];
#pragma unroll
    for (int e = 0; e < 8; ++e) lg[e] = acc[e] + gb[e];
    int e0 = 0; float v0 = lg[0];
#pragma unroll
    for (int e = 1; e < 8; ++e) if (lg[e] > v0) { v0 = lg[e]; e0 = e; }
    int e1 = -1; float v1 = -3e38f;
#pragma unroll
    for (int e = 0; e < 8; ++e) if (e != e0 && lg[e] > v1) { v1 = lg[e]; e1 = e; }
    float ed = expf(v1 - v0);
    float si = 1.0f / (1.0f + ed);
    sel[r] = make_int2(e0, e1);
    wgt[r] = make_float2(si, ed * si);
  }
}

__global__ void kCount(const int2* __restrict__ sel, int* __restrict__ cnt) {
  int r = blockIdx.x * 256 + threadIdx.x;
  if (r < 4096) { int2 s = sel[r]; atomicAdd(&cnt[s.x], 1); atomicAdd(&cnt[s.y], 1); }
}
// 128-aligned per-expert offsets + compact tile map
__global__ void kScan(const int* __restrict__ cnt, int* __restrict__ off,
                      int2* __restrict__ tmap, int* __restrict__ tn) {
  if (threadIdx.x == 0) {
    int run = 0, nt = 0;
    for (int e = 0; e < 8; ++e) {
      off[e] = run;
      int nb = (cnt[e] + 127) >> 7;
      for (int j = 0; j < nb; ++j) { tmap[nt] = make_int2(e, run + (j << 7)); ++nt; }
      run += nb << 7;
    }
    *tn = nt;
  }
}
__global__ void kScatter(const int2* __restrict__ sel, const int* __restrict__ off,
                         int* __restrict__ cur, int* __restrict__ bucket, int2* __restrict__ slotof) {
  int r = blockIdx.x * 256 + threadIdx.x;
  if (r < 4096) {
    int2 s = sel[r];
    int a0 = off[s.x] + atomicAdd(&cur[s.x], 1);
    int a1 = off[s.y] + atomicAdd(&cur[s.y], 1);
    bucket[a0] = r; bucket[a1] = r;
    slotof[r] = make_int2(a0, a1);
  }
}

__global__ __launch_bounds__(256) void kCombine(const float* __restrict__ Z, const int2* __restrict__ slotof,
                                                const float2* __restrict__ wgt, const float* __restrict__ mom_in,
                                                float* __restrict__ mom_out) {
  const long r = blockIdx.x;
  const int t = threadIdx.x;
  int2 sl = slotof[r];
  float2 w = wgt[r];
  const float* z0 = Z + (long)sl.x * 1024;
  const float* z1 = Z + (long)sl.y * 1024;
#pragma unroll
  for (int i = 0; i < 4; ++i) {
    int c = t + i * 256;
    float moe = w.x * z0[c] + w.y * z1[c];
    mom_out[r * 1024 + c] = 0.7f * mom_in[r * 1024 + c] + moe;
  }
}

// ---------------------------------------------------------------------------
extern "C" void kernel_launch(void* const* d_in, const int* in_sizes, int n_in,
                              void* d_out, int out_size, void* d_ws, size_t ws_size,
                              hipStream_t stream) {
  (void)in_sizes; (void)n_in; (void)out_size; (void)ws_size;
  const float* h       = (const float*)d_in[0];
  const float* h_cache = (const float*)d_in[1];
  const float* pos     = (const float*)d_in[2];
  const float* mom_in  = (const float*)d_in[3];
  const float* Wq      = (const float*)d_in[4];
  const float* Wk      = (const float*)d_in[5];
  const float* Wv      = (const float*)d_in[6];
  const float* Wo      = (const float*)d_in[7];
  const float* gate_w  = (const float*)d_in[8];
  const float* gate_b  = (const float*)d_in[9];
  const float* w1      = (const float*)d_in[10];
  const float* b1      = (const float*)d_in[11];
  const float* w2      = (const float*)d_in[12];
  const float* b2      = (const float*)d_in[13];
  const float* ln1g    = (const float*)d_in[14];
  const float* ln1b    = (const float*)d_in[15];
  const float* ln2g    = (const float*)d_in[16];
  const float* ln2b    = (const float*)d_in[17];
  float* out = (float*)d_out;

  char* ws = (char*)d_ws;
  // Phase-aliased region map (total ~391 MB). Lifetimes commented.
  float*          S     = (float*)(ws + 0L);               // ph2 per half
  unsigned short* Y1    = (unsigned short*)(ws + 0L);      // ph5 (9216x4096)
  unsigned short* Oh    = (unsigned short*)(ws + 0L);      // ph3
  unsigned short* Ol    = (unsigned short*)(ws + 8388608L);
  float*          Ppos  = (float*)(ws + 75497472L);        // ph2
  unsigned short* w1T   = (unsigned short*)(ws + 75497472L);   // ph5
  unsigned short* Ph    = (unsigned short*)(ws + 142606336L);  // ph2
  unsigned short* Pl    = (unsigned short*)(ws + 180355072L);
  unsigned short* w2T   = (unsigned short*)(ws + 142606336L);  // ph5
  unsigned short* Xh    = (unsigned short*)(ws + 218103808L);  // ph0-1
  unsigned short* Xl    = (unsigned short*)(ws + 234881024L);
  float*          attnO = (float*)(ws + 218103808L);       // ph2-3 (alias Xh)
  float*          attnWo= (float*)(ws + 234881024L);       // ph3 (alias Xl)
  unsigned short* kh    = (unsigned short*)(ws + 251658240L);  // ph1-2
  unsigned short* kl    = (unsigned short*)(ws + 268435456L);
  float*          h1f   = (float*)(ws + 251658240L);       // ph3+ (alias kh)
  unsigned short* h1h   = (unsigned short*)(ws + 268435456L);  // ph3+ (alias kl)
  unsigned short* VTh   = (unsigned short*)(ws + 285212672L);  // ph1-2
  unsigned short* VTl   = (unsigned short*)(ws + 301989888L);
  unsigned short* qh    = (unsigned short*)(ws + 318767104L);  // ph1-2
  unsigned short* ql    = (unsigned short*)(ws + 327155712L);
  float*          qtmp  = (float*)(ws + 335544320L);       // ph1
  float*          Z     = (float*)(ws + 335544320L);       // ph5-6 (9216x1024)
  unsigned short* WqTh  = (unsigned short*)(ws + 373293056L);
  unsigned short* WqTl  = (unsigned short*)(ws + 375390208L);
  unsigned short* WkTh  = (unsigned short*)(ws + 377487360L);
  unsigned short* WkTl  = (unsigned short*)(ws + 379584512L);
  unsigned short* WvTh  = (unsigned short*)(ws + 381681664L);
  unsigned short* WvTl  = (unsigned short*)(ws + 383778816L);
  unsigned short* WoTh  = (unsigned short*)(ws + 385875968L);
  unsigned short* WoTl  = (unsigned short*)(ws + 387973120L);
  unsigned short* posTh = (unsigned short*)(ws + 390070272L);
  unsigned short* posTl = (unsigned short*)(ws + 390332416L);
  int2*           sel   = (int2*)(ws + 390594560L);
  float2*         wgt   = (float2*)(ws + 390627328L);
  int2*           slotof= (int2*)(ws + 390660096L);
  int*            bucket= (int*)(ws + 390692864L);         // 9216 ints
  int*            cnt   = (int*)(ws + 390729728L);
  int*            cur   = (int*)(ws + 390729760L);
  int*            off   = (int*)(ws + 390729792L);
  int2*           tmap  = (int2*)(ws + 390729856L);        // 80 tiles
  int*            tn    = (int*)(ws + 390730496L);

  // ---- phase 0: concat+split X, transpose+split weights / pos ----
  kConcatSplit<<<8192, 256, 0, stream>>>(h, h_cache, Xh, Xl);
  kTransposeSplit<<<dim3(32, 32, 1), 256, 0, stream>>>(Wq, 0, 1024, 1024, WqTh, WqTl, 0);
  kTransposeSplit<<<dim3(32, 32, 1), 256, 0, stream>>>(Wk, 0, 1024, 1024, WkTh, WkTl, 0);
  kTransposeSplit<<<dim3(32, 32, 1), 256, 0, stream>>>(Wv, 0, 1024, 1024, WvTh, WvTl, 0);
  kTransposeSplit<<<dim3(32, 32, 1), 256, 0, stream>>>(Wo, 0, 1024, 1024, WoTh, WoTl, 0);
  kTransposeSplit<<<dim3(32, 4, 1), 256, 0, stream>>>(pos, 0, 128, 1024, posTh, posTl, 0);

  // ---- phase 1: projections ----
  hipMemsetAsync(qtmp, 0, 16777216L, stream);
  {  // qtmp = h @ Wq (fp32 atomic, K-split 2)
    GemmP p{}; p.zdiv = 1; p.split = 1; p.mode = 5;
    p.Ah = Xh + 1048576; p.Al = Xl + 1048576; p.Bh = WqTh; p.Bl = WqTl;
    p.C = qtmp;
    p.lda = 1024; p.ldb = 1024; p.ldc = 1024; p.K = 1024; p.Kc = 512; p.nx = 8;
    p.a_zo = 2097152; p.c_zo = 1048576; p.c_y = 131072; p.c_x = 128;
    kGemm<1><<<dim3(16, 8, 4), 256, 0, stream>>>(p);
  }
  kSplitF<<<4096, 256, 0, stream>>>(qtmp, qh, ql, 1048576);
  {  // k = X @ Wk (split store)
    GemmP p{}; p.zdiv = 1; p.split = 1; p.mode = 1;
    p.Ah = Xh; p.Al = Xl; p.Bh = WkTh; p.Bl = WkTl;
    p.C = kh; p.C2 = kl;
    p.lda = 1024; p.ldb = 1024; p.ldc = 1024; p.K = 1024; p.Kc = 1024; p.nx = 8;
    p.c_y = 131072; p.c_x = 128;
    kGemm<1><<<dim3(8, 64, 1), 256, 0, stream>>>(p);
  }
  {  // VT = (X @ Wv)^T per batch: [b][hd*128+d][key]
    GemmP p{}; p.zdiv = 1; p.split = 1; p.mode = 2;
    p.Ah = Xh; p.Al = Xl; p.Bh = WvTh; p.Bl = WvTl;
    p.C = VTh; p.C2 = VTl;
    p.lda = 1024; p.ldb = 1024; p.ldc = 2048; p.K = 1024; p.Kc = 1024; p.nx = 8;
    p.a_zo = 2097152; p.c_zo = 2097152; p.c_y = 128; p.c_x = 262144;
    kGemm<1><<<dim3(8, 16, 4), 256, 0, stream>>>(p);
  }

  // ---- phase 2: attention, per batch-half (z = 16 heads) ----
  hipMemsetAsync(attnO, 0, 16777216L, stream);
  for (int hf = 0; hf < 2; ++hf) {
    const long qo = hf * 2097152L, ko = hf * 4194304L, vo = hf * 4194304L;
    {  // Ppos[z][m][l] = q . posT[l]
      GemmP p{}; p.zdiv = 8; p.split = 1; p.mode = 0;
      p.Ah = qh + qo; p.Al = ql + qo; p.Bh = posTh; p.Bl = posTl;
      p.C = Ppos;
      p.lda = 1024; p.ldb = 128; p.ldc = 1024; p.K = 128; p.Kc = 128; p.nx = 8;
      p.a_zo = 1048576; p.a_zi = 128;
      p.c_zo = 8388608; p.c_zi = 1048576; p.c_y = 131072; p.c_x = 128;
      kGemm<1><<<dim3(8, 8, 16), 256, 0, stream>>>(p);
    }
    {  // banded scores with fused skew lookup + mask + 1/32
      GemmP p{}; p.zdiv = 8; p.split = 1; p.mode = 3;
      p.Ah = qh + qo; p.Al = ql + qo; p.Bh = kh + ko; p.Bl = kl + ko;
      p.C = S; p.xtra = Ppos;
      p.lda = 1024; p.ldb = 1024; p.ldc = 1152; p.xld = 1024; p.K = 128; p.Kc = 128; p.nx = 9;
      p.a_zo = 1048576; p.a_zi = 128;
      p.b_zo = 2097152; p.b_zi = 128; p.b_y = 131072;
      p.c_zo = 9437184; p.c_zi = 1179648; p.c_y = 147456; p.c_x = 128;
      p.x_zo = 8388608; p.x_zi = 1048576; p.x_y = 131072;
      kGemm<1><<<dim3(9, 8, 16), 256, 0, stream>>>(p);
    }
    kSoftmax<<<16384, 256, 0, stream>>>(S, Ph, Pl);
    {  // attnO += P @ V (K-split 3, fp32 atomic)
      GemmP p{}; p.zdiv = 8; p.split = 1; p.mode = 5;
      p.Ah = Ph; p.Al = Pl; p.Bh = VTh + vo; p.Bl = VTl + vo;
      p.C = attnO + hf * 2097152L;
      p.lda = 1152; p.ldb = 2048; p.ldc = 1024; p.K = 1152; p.Kc = 384; p.nx = 1;
      p.a_zo = 9437184; p.a_zi = 1179648;
      p.b_zo = 2097152; p.b_zi = 262144; p.b_y = 128;
      p.c_zo = 1048576; p.c_zi = 128; p.c_y = 131072; p.c_x = 128;
      kGemm<1><<<dim3(3, 8, 16), 256, 0, stream>>>(p);
    }
  }

  // ---- phase 3: O split + Wo projection (K-split 2) + LN1 ----
  kSplitF<<<4096, 256, 0, stream>>>(attnO, Oh, Ol, 1048576);
  hipMemsetAsync(attnWo, 0, 16777216L, stream);
  {
    GemmP p{}; p.zdiv = 1; p.split = 1; p.mode = 5;
    p.Ah = Oh; p.Al = Ol; p.Bh = WoTh; p.Bl = WoTl;
    p.C = attnWo;
    p.lda = 1024; p.ldb = 1024; p.ldc = 1024; p.K = 1024; p.Kc = 512; p.nx = 8;
    p.c_y = 131072; p.c_x = 128;
    kGemm<1><<<dim3(16, 32, 1), 256, 0, stream>>>(p);
  }
  kLN1<<<4096, 256, 0, stream>>>(h, attnWo, ln1g, ln1b, h1f, h1h);

  // ---- phase 4: gate + compact buckets ----
  kGate<<<1024, 256, 0, stream>>>(h1f, gate_w, gate_b, sel, wgt);
  hipMemsetAsync(cnt, 0, 64, stream);              // cnt + cur
  hipMemsetAsync(bucket, 0, 36864, stream);        // pad slots -> row 0
  kCount<<<16, 256, 0, stream>>>(sel, cnt);
  kScan<<<1, 64, 0, stream>>>(cnt, off, tmap, tn);
  kScatter<<<16, 256, 0, stream>>>(sel, off, cur, bucket, slotof);

  // ---- phase 5: MoE (single bf16, compact tile map, wide 128x256 tiles) ----
  kTransposeSplit<<<dim3(128, 32, 8), 256, 0, stream>>>(w1, 4194304L, 1024, 4096, w1T, nullptr, 4194304L);
  kTransposeSplit<<<dim3(32, 128, 8), 256, 0, stream>>>(w2, 4194304L, 4096, 1024, w2T, nullptr, 4194304L);
  {  // Y1 = relu(gather(h1) @ w1[e] + b1[e]) — BN=256, nx=16
    GemmP p{}; p.zdiv = 1; p.split = 0; p.mode = 4;
    p.Ah = h1h; p.Bh = w1T;
    p.C = Y1;
    p.idx = bucket; p.tmap = tmap; p.tn = tn;
    p.bias = b1; p.bias_z = 4096;
    p.lda = 1024; p.ldb = 1024; p.ldc = 4096; p.K = 1024; p.Kc = 1024; p.nx = 16;
    p.b_zi = 4194304; p.c_x = 256;
    kGemmW<<<dim3(16, 72, 1), 512, 0, stream>>>(p);
  }
  hipMemsetAsync(Z, 0, 37748736L, stream);
  {  // Z += Y1 @ w2[e] + b2[e]  (K-split 2, fp32 atomic) — BN=256, nx=4
    GemmP p{}; p.zdiv = 1; p.split = 0; p.mode = 5;
    p.Ah = Y1; p.Bh = w2T;
    p.C = Z;
    p.tmap = tmap; p.tn = tn;
    p.bias = b2; p.bias_z = 1024;
    p.lda = 4096; p.ldb = 4096; p.ldc = 1024; p.K = 4096; p.Kc = 2048; p.nx = 4;
    p.b_zi = 4194304; p.c_x = 256;
    kGemmW<<<dim3(8, 72, 1), 512, 0, stream>>>(p);
  }

  // ---- phase 6: combine + momentum + LN2 ----
  float* mom_out = out + 4194304;
  kCombine<<<4096, 256, 0, stream>>>(Z, slotof, wgt, mom_in, mom_out);
  kLN2<<<4096, 256, 0, stream>>>(h1f, mom_out, ln2g, ln2b, out);
}